// Round 4
// baseline (435.497 us; speedup 1.0000x reference)
//
#include <hip/hip_runtime.h>

#define LL 2048
#define HH 2048
#define EE 4096
#define NS 16
#define RR 128
#define CT 32            // chunk timesteps
#define NC (LL / CT)     // 64 chunks
#define BM 128
#define BN 128
#define BK 64

typedef __bf16 bf16x8 __attribute__((ext_vector_type(8)));
typedef float f32x4 __attribute__((ext_vector_type(4)));

__device__ __forceinline__ unsigned short f2bf(float f) {
  union { float f; unsigned int u; } v; v.f = f;
  unsigned int r = v.u + 0x7fffu + ((v.u >> 16) & 1u);
  return (unsigned short)(r >> 16);
}

__device__ __forceinline__ float bf2f(unsigned short u) {
  union { unsigned int i; float f; } v;
  v.i = ((unsigned int)u) << 16;
  return v.f;
}

// softplus via native transcendentals only (NO libm log1pf — it's a non-inline
// ocml call that forces VGPR save/restore in high-pressure epilogues)
__device__ __forceinline__ float softplus_fast(float x) {
  if (x > 20.0f) return x;
  float e = __builtin_amdgcn_exp2f(1.44269504f * x);
  return 0.69314718f * __builtin_amdgcn_logf(1.0f + e);
}

__device__ __forceinline__ void async_cp16(const unsigned short* g,
                                           unsigned short* l) {
  __builtin_amdgcn_global_load_lds(
      (const __attribute__((address_space(1))) unsigned int*)g,
      (__attribute__((address_space(3))) unsigned int*)l, 16, 0, 0);
}

// ============ fused prep: 5 bf16 casts + 2 zero fills, ONE launch ==========
// All boundaries are multiples of 256 (whole blocks per segment -> no
// divergence). float4/ushort4 vectorized.
#define P_C0 (LL * HH / 4)               // hs -> hsb        1048576
#define P_C1 (P_C0 + 2 * EE * HH / 4)    // w1 -> w1b        5242880
#define P_C2 (P_C1 + 160 * EE / 4)       // xw -> xwb        5406720
#define P_C3 (P_C2 + EE * RR / 4)        // dtw -> dtwb      5537792
#define P_C4 (P_C3 + HH * EE / 4)        // ow -> owb        7634944
#define P_C5 (P_C4 + LL * 160 / 4)       // zero ssm         7716864
#define P_C6 (P_C5 + LL * HH / 4)        // zero out         8765440

__global__ __launch_bounds__(256) void prep_k(
    const float* __restrict__ hs, unsigned short* __restrict__ hsb,
    const float* __restrict__ w1, unsigned short* __restrict__ w1b,
    const float* __restrict__ xw, unsigned short* __restrict__ xwb,
    const float* __restrict__ dtw, unsigned short* __restrict__ dtwb,
    const float* __restrict__ ow, unsigned short* __restrict__ owb,
    float* __restrict__ ssm, float* __restrict__ out) {
  int i = blockIdx.x * 256 + threadIdx.x;
  const float* src = nullptr;
  unsigned short* dst = nullptr;
  int k = 0;
  if (i < P_C0)      { src = hs;  dst = hsb;  k = i; }
  else if (i < P_C1) { src = w1;  dst = w1b;  k = i - P_C0; }
  else if (i < P_C2) { src = xw;  dst = xwb;  k = i - P_C1; }
  else if (i < P_C3) { src = dtw; dst = dtwb; k = i - P_C2; }
  else if (i < P_C4) { src = ow;  dst = owb;  k = i - P_C3; }
  else if (i < P_C5) {
    float4 z; z.x = z.y = z.z = z.w = 0.0f;
    reinterpret_cast<float4*>(ssm)[i - P_C4] = z;
    return;
  } else {
    float4 z; z.x = z.y = z.z = z.w = 0.0f;
    reinterpret_cast<float4*>(out)[i - P_C5] = z;
    return;
  }
  float4 v = reinterpret_cast<const float4*>(src)[k];
  ushort4 o;
  o.x = f2bf(v.x); o.y = f2bf(v.y); o.z = f2bf(v.z); o.w = f2bf(v.w);
  reinterpret_cast<ushort4*>(dst)[k] = o;
}

// ============= 256x256 8-phase BT-GEMM (faithful m201-style) ===============
// C[M,N] = A[M,K] * B[N,K]^T, bf16 in / f32 acc. 512 threads = 8 waves (2Mx4N),
// per-wave 128x64 output. BK=64, double-buffered LDS (128 KiB): buf0 = even
// K-tiles, buf1 = odd. Iteration = 2 K-tiles (t0 even, t1=t0+1), 8 phases.
// Each phase: {ds_read subtile; stage 1 half-tile into DEAD region; barrier;
// lgkm0; setprio1; 16 MFMA (kk-outer -> dep distance 8); setprio0; barrier}.
// Counted waits ONLY (never drain in steady state):
//   end p3: vmcnt(4)  [newest 4 = B(t0+2) stages; everything t1 needs landed]
//   end p7: vmcnt(6)  [newest 6 = B(t1+2)+A(t1+2)h0; next pair's t0 landed]
// Stage slots (half-tile = 2 gloads; deadness via preceding end-barrier):
//   p0: A(t1)h1 | p2: B(t0+2)h0 | p3: B(t0+2)h1 | p4: A(t0+2)h0
//   p5: A(t0+2)h1 | p6: B(t1+2)h0 | p7: B(t1+2)h1 + A(t1+2)h0
// LDS swizzle: 16B-block XOR by row&7, both-sides. SQ_LDS_BANK_CONFLICT=0.
// EPI: 1 = f32 atomicAdd (split-K)
//      2 = in_proj (cols<EE -> f32 auxF; cols>=EE -> silu bf16 auxB)
template <int EPI>
__global__ __launch_bounds__(512, 2) void gemm256(
    const unsigned short* __restrict__ A,
    const unsigned short* __restrict__ B,
    float* __restrict__ C,
    int M, int N, int K, int tilesM, int splitk,
    float* __restrict__ auxF, unsigned short* __restrict__ auxB) {
  __shared__ __align__(16) unsigned short As[2][16384];
  __shared__ __align__(16) unsigned short Bs[2][16384];

  int bid = blockIdx.x;
  int tnInner = bid & 7;             // XCD-locality
  int rest = bid >> 3;
  int tm = rest % tilesM;
  int tn = (rest / tilesM) * 8 + tnInner;

  int Kslice = K / splitk;
  int k_begin = blockIdx.y * Kslice;
  int NT = Kslice / 64;              // even, >= 2

  int tid = threadIdx.x;
  int lane = tid & 63;
  int wave = tid >> 6;               // 0..7
  int wm = wave >> 2;                // 0..1
  int wn = wave & 3;                 // 0..3
  int m16 = lane & 15, quad = lane >> 4;

  const unsigned short* Ab = A + (size_t)tm * 256 * K;
  const unsigned short* Bb = B + (size_t)tn * 256 * K;

  // staging geometry: one call = 512 threads x 16B = 64 rows x 64 cols
  int rowS = tid >> 3;
  int gcbS = (tid & 7) ^ (rowS & 7);
  int ldsWB = (tid & ~63) * 8;

  // ds_read fragment addressing (ushort offsets)
  int sw = m16 & 7;
  int coff0 = (quad ^ sw) << 3;
  int coff1 = ((4 + quad) ^ sw) << 3;
  int aoff = (wm * 128 + m16) * 64;
  int boff = (wn * 64 + m16) * 64;

  f32x4 acc[8][4];
#pragma unroll
  for (int i = 0; i < 8; ++i)
#pragma unroll
    for (int j = 0; j < 4; ++j)
#pragma unroll
      for (int t = 0; t < 4; ++t) acc[i][j][t] = 0.0f;

  // half-tile stagers: h in {0,1} -> chunks {2h, 2h+1} (rows h*128..h*128+127)
  auto stageA = [&](int bufb, int t, int h) {
    int kt = k_begin + t * 64;
    unsigned short* dst = &As[bufb][0];
#pragma unroll
    for (int c = 2 * h; c < 2 * h + 2; ++c)
      async_cp16(Ab + (size_t)(c * 64 + rowS) * K + kt + gcbS * 8,
                 dst + c * 4096 + ldsWB);
  };
  auto stageB = [&](int bufb, int t, int h) {
    int kt = k_begin + t * 64;
    unsigned short* dst = &Bs[bufb][0];
#pragma unroll
    for (int c = 2 * h; c < 2 * h + 2; ++c)
      async_cp16(Bb + (size_t)(c * 64 + rowS) * K + kt + gcbS * 8,
                 dst + c * 4096 + ldsWB);
  };

  // ---- prologue: tile0 full (8), then B(1)h0,h1 + A(1)h0 (6); vmcnt(6) ----
  stageA(0, 0, 0); stageA(0, 0, 1);
  stageB(0, 0, 0); stageB(0, 0, 1);
  stageB(1, 1, 0); stageB(1, 1, 1);
  stageA(1, 1, 0);
  asm volatile("s_waitcnt vmcnt(6)" ::: "memory");
  __builtin_amdgcn_s_barrier();

  bf16x8 a[4][2], b0[2][2], b1[2][2];

  for (int t0 = 0; t0 < NT; t0 += 2) {
    int t1 = t0 + 1;
    bool notLast = (t0 + 2 < NT);
    unsigned short* A0 = &As[0][0];
    unsigned short* B0 = &Bs[0][0];
    unsigned short* A1 = &As[1][0];
    unsigned short* B1 = &Bs[1][0];

    // ================= K-tile t0 (buf0), phases p0..p3 =================
    // ---- p0: reads a-lo + b0; stage A(t1)h1; MFMA q00 ----
#pragma unroll
    for (int i = 0; i < 4; ++i) {
      a[i][0] = *reinterpret_cast<const bf16x8*>(&A0[aoff + i * 1024 + coff0]);
      a[i][1] = *reinterpret_cast<const bf16x8*>(&A0[aoff + i * 1024 + coff1]);
    }
#pragma unroll
    for (int j = 0; j < 2; ++j) {
      b0[j][0] = *reinterpret_cast<const bf16x8*>(&B0[boff + j * 1024 + coff0]);
      b0[j][1] = *reinterpret_cast<const bf16x8*>(&B0[boff + j * 1024 + coff1]);
    }
    stageA(1, t1, 1);
    __builtin_amdgcn_s_barrier();
    asm volatile("s_waitcnt lgkmcnt(0)" ::: "memory");
    __builtin_amdgcn_sched_barrier(0);
    __builtin_amdgcn_s_setprio(1);
#pragma unroll
    for (int kk = 0; kk < 2; ++kk)
#pragma unroll
      for (int i = 0; i < 4; ++i)
#pragma unroll
        for (int j = 0; j < 2; ++j)
          acc[i][j] = __builtin_amdgcn_mfma_f32_16x16x32_bf16(
              a[i][kk], b0[j][kk], acc[i][j], 0, 0, 0);
    __builtin_amdgcn_s_setprio(0);
    __builtin_amdgcn_s_barrier();

    // ---- p1: reads b1; MFMA q01 ----
#pragma unroll
    for (int j = 0; j < 2; ++j) {
      b1[j][0] = *reinterpret_cast<const bf16x8*>(&B0[boff + (2 + j) * 1024 + coff0]);
      b1[j][1] = *reinterpret_cast<const bf16x8*>(&B0[boff + (2 + j) * 1024 + coff1]);
    }
    __builtin_amdgcn_s_barrier();
    asm volatile("s_waitcnt lgkmcnt(0)" ::: "memory");
    __builtin_amdgcn_sched_barrier(0);
    __builtin_amdgcn_s_setprio(1);
#pragma unroll
    for (int kk = 0; kk < 2; ++kk)
#pragma unroll
      for (int i = 0; i < 4; ++i)
#pragma unroll
        for (int j = 0; j < 2; ++j)
          acc[i][2 + j] = __builtin_amdgcn_mfma_f32_16x16x32_bf16(
              a[i][kk], b1[j][kk], acc[i][2 + j], 0, 0, 0);
    __builtin_amdgcn_s_setprio(0);
    __builtin_amdgcn_s_barrier();

    // ---- p2: reads a-hi; stage B(t0+2)h0 (B-buf0 dead); MFMA q11 ----
#pragma unroll
    for (int i = 0; i < 4; ++i) {
      a[i][0] = *reinterpret_cast<const bf16x8*>(&A0[aoff + (4 + i) * 1024 + coff0]);
      a[i][1] = *reinterpret_cast<const bf16x8*>(&A0[aoff + (4 + i) * 1024 + coff1]);
    }
    if (notLast) stageB(0, t0 + 2, 0);
    __builtin_amdgcn_s_barrier();
    asm volatile("s_waitcnt lgkmcnt(0)" ::: "memory");
    __builtin_amdgcn_sched_barrier(0);
    __builtin_amdgcn_s_setprio(1);
#pragma unroll
    for (int kk = 0; kk < 2; ++kk)
#pragma unroll
      for (int i = 0; i < 4; ++i)
#pragma unroll
        for (int j = 0; j < 2; ++j)
          acc[4 + i][2 + j] = __builtin_amdgcn_mfma_f32_16x16x32_bf16(
              a[i][kk], b1[j][kk], acc[4 + i][2 + j], 0, 0, 0);
    __builtin_amdgcn_s_setprio(0);
    __builtin_amdgcn_s_barrier();

    // ---- p3: no reads (b0 in regs); stage B(t0+2)h1; MFMA q10; vmcnt(4) ----
    if (notLast) stageB(0, t0 + 2, 1);
    __builtin_amdgcn_s_setprio(1);
#pragma unroll
    for (int kk = 0; kk < 2; ++kk)
#pragma unroll
      for (int i = 0; i < 4; ++i)
#pragma unroll
        for (int j = 0; j < 2; ++j)
          acc[4 + i][j] = __builtin_amdgcn_mfma_f32_16x16x32_bf16(
              a[i][kk], b0[j][kk], acc[4 + i][j], 0, 0, 0);
    __builtin_amdgcn_s_setprio(0);
    if (notLast) {
      asm volatile("s_waitcnt vmcnt(4)" ::: "memory");
    } else {
      asm volatile("s_waitcnt vmcnt(0)" ::: "memory");
    }
    __builtin_amdgcn_s_barrier();

    // ================= K-tile t1 (buf1), phases p4..p7 =================
    // ---- p4: reads a-lo + b0; stage A(t0+2)h0 (A-buf0 dead); MFMA q00 ----
#pragma unroll
    for (int i = 0; i < 4; ++i) {
      a[i][0] = *reinterpret_cast<const bf16x8*>(&A1[aoff + i * 1024 + coff0]);
      a[i][1] = *reinterpret_cast<const bf16x8*>(&A1[aoff + i * 1024 + coff1]);
    }
#pragma unroll
    for (int j = 0; j < 2; ++j) {
      b0[j][0] = *reinterpret_cast<const bf16x8*>(&B1[boff + j * 1024 + coff0]);
      b0[j][1] = *reinterpret_cast<const bf16x8*>(&B1[boff + j * 1024 + coff1]);
    }
    if (notLast) stageA(0, t0 + 2, 0);
    __builtin_amdgcn_s_barrier();
    asm volatile("s_waitcnt lgkmcnt(0)" ::: "memory");
    __builtin_amdgcn_sched_barrier(0);
    __builtin_amdgcn_s_setprio(1);
#pragma unroll
    for (int kk = 0; kk < 2; ++kk)
#pragma unroll
      for (int i = 0; i < 4; ++i)
#pragma unroll
        for (int j = 0; j < 2; ++j)
          acc[i][j] = __builtin_amdgcn_mfma_f32_16x16x32_bf16(
              a[i][kk], b0[j][kk], acc[i][j], 0, 0, 0);
    __builtin_amdgcn_s_setprio(0);
    __builtin_amdgcn_s_barrier();

    // ---- p5: reads b1; stage A(t0+2)h1; MFMA q01 ----
#pragma unroll
    for (int j = 0; j < 2; ++j) {
      b1[j][0] = *reinterpret_cast<const bf16x8*>(&B1[boff + (2 + j) * 1024 + coff0]);
      b1[j][1] = *reinterpret_cast<const bf16x8*>(&B1[boff + (2 + j) * 1024 + coff1]);
    }
    if (notLast) stageA(0, t0 + 2, 1);
    __builtin_amdgcn_s_barrier();
    asm volatile("s_waitcnt lgkmcnt(0)" ::: "memory");
    __builtin_amdgcn_sched_barrier(0);
    __builtin_amdgcn_s_setprio(1);
#pragma unroll
    for (int kk = 0; kk < 2; ++kk)
#pragma unroll
      for (int i = 0; i < 4; ++i)
#pragma unroll
        for (int j = 0; j < 2; ++j)
          acc[i][2 + j] = __builtin_amdgcn_mfma_f32_16x16x32_bf16(
              a[i][kk], b1[j][kk], acc[i][2 + j], 0, 0, 0);
    __builtin_amdgcn_s_setprio(0);
    __builtin_amdgcn_s_barrier();

    // ---- p6: reads a-hi; stage B(t1+2)h0; MFMA q11 ----
#pragma unroll
    for (int i = 0; i < 4; ++i) {
      a[i][0] = *reinterpret_cast<const bf16x8*>(&A1[aoff + (4 + i) * 1024 + coff0]);
      a[i][1] = *reinterpret_cast<const bf16x8*>(&A1[aoff + (4 + i) * 1024 + coff1]);
    }
    if (notLast) stageB(1, t1 + 2, 0);
    __builtin_amdgcn_s_barrier();
    asm volatile("s_waitcnt lgkmcnt(0)" ::: "memory");
    __builtin_amdgcn_sched_barrier(0);
    __builtin_amdgcn_s_setprio(1);
#pragma unroll
    for (int kk = 0; kk < 2; ++kk)
#pragma unroll
      for (int i = 0; i < 4; ++i)
#pragma unroll
        for (int j = 0; j < 2; ++j)
          acc[4 + i][2 + j] = __builtin_amdgcn_mfma_f32_16x16x32_bf16(
              a[i][kk], b1[j][kk], acc[4 + i][2 + j], 0, 0, 0);
    __builtin_amdgcn_s_setprio(0);
    __builtin_amdgcn_s_barrier();

    // ---- p7: no reads; stage B(t1+2)h1 + A(t1+2)h0; MFMA q10; vmcnt(6) ----
    if (notLast) { stageB(1, t1 + 2, 1); stageA(1, t1 + 2, 0); }
    __builtin_amdgcn_s_setprio(1);
#pragma unroll
    for (int kk = 0; kk < 2; ++kk)
#pragma unroll
      for (int i = 0; i < 4; ++i)
#pragma unroll
        for (int j = 0; j < 2; ++j)
          acc[4 + i][j] = __builtin_amdgcn_mfma_f32_16x16x32_bf16(
              a[i][kk], b0[j][kk], acc[4 + i][j], 0, 0, 0);
    __builtin_amdgcn_s_setprio(0);
    if (notLast) {
      asm volatile("s_waitcnt vmcnt(6)" ::: "memory");
    }
    __builtin_amdgcn_s_barrier();
  }

  // ---------------- epilogue ----------------
  int rowB = tm * 256 + wm * 128;
  int colB = tn * 256 + wn * 64;
  if constexpr (EPI == 1) {
#pragma unroll
    for (int mi = 0; mi < 8; ++mi)
#pragma unroll
      for (int nj = 0; nj < 4; ++nj) {
        int col = colB + nj * 16 + m16;
        int row0 = rowB + mi * 16 + quad * 4;
#pragma unroll
        for (int t4 = 0; t4 < 4; ++t4)
          atomicAdd(&C[(size_t)(row0 + t4) * N + col], acc[mi][nj][t4]);
      }
  } else {  // EPI == 2: in_proj epilogue
    if (colB < EE) {
#pragma unroll
      for (int mi = 0; mi < 8; ++mi)
#pragma unroll
        for (int nj = 0; nj < 4; ++nj) {
          int col = colB + nj * 16 + m16;
          int row0 = rowB + mi * 16 + quad * 4;
#pragma unroll
          for (int t4 = 0; t4 < 4; ++t4)
            auxF[(size_t)(row0 + t4) * EE + col] = acc[mi][nj][t4];
        }
    } else {
#pragma unroll
      for (int mi = 0; mi < 8; ++mi)
#pragma unroll
        for (int nj = 0; nj < 4; ++nj) {
          int cg = colB + nj * 16 + m16 - EE;
          int row0 = rowB + mi * 16 + quad * 4;
#pragma unroll
          for (int t4 = 0; t4 < 4; ++t4) {
            float v = acc[mi][nj][t4];
            float s = v / (1.0f + __expf(-v));
            auxB[(size_t)(row0 + t4) * EE + cg] = f2bf(s);
          }
        }
    }
  }
}

// ============ LDS-staged bf16 BT-GEMM (128x128) — dt_proj ==================
// EPI 4 = +bias[col], softplus, bf16 store to auxB (K=128: too shallow for the
// 256^2 pipeline, staging-dominated; keep the simple structure)
template <int EPI>
__global__ __launch_bounds__(256) void gemm_lds_t(
    const unsigned short* __restrict__ A,
    const unsigned short* __restrict__ B,
    float* __restrict__ C,
    int M, int N, int K, int tilesM, int splitk,
    const float* __restrict__ bias, float* __restrict__ auxF,
    unsigned short* __restrict__ auxB) {
  __shared__ __align__(16) unsigned short As[BM * BK];
  __shared__ __align__(16) unsigned short Bs[BN * BK];

  int bid = blockIdx.x;
  int tnInner = bid & 7;
  int rest = bid >> 3;
  int tm = rest % tilesM;
  int tnOuter = rest / tilesM;
  int tn = tnOuter * 8 + tnInner;

  int Kslice = K / splitk;
  int k_begin = blockIdx.y * Kslice;
  int k_end = k_begin + Kslice;

  int tid = threadIdx.x;
  int lane = tid & 63;
  int wave = tid >> 6;
  int wm = wave & 1, wn = wave >> 1;
  int m16 = lane & 15, quad = lane >> 4;

  const unsigned short* Ab = A + (size_t)tm * BM * K;
  const unsigned short* Bb = B + (size_t)tn * BN * K;

  int srow[4], sgcb[4];
#pragma unroll
  for (int it = 0; it < 4; ++it) {
    int blk = it * 256 + tid;
    srow[it] = blk >> 3;
    sgcb[it] = (blk & 7) ^ (srow[it] & 7);
  }
  int ldsbase = (tid & ~63) * 8;

  f32x4 acc[4][4];
#pragma unroll
  for (int i = 0; i < 4; ++i)
#pragma unroll
    for (int j = 0; j < 4; ++j)
#pragma unroll
      for (int t = 0; t < 4; ++t) acc[i][j][t] = 0.0f;

  for (int k0 = k_begin; k0 < k_end; k0 += BK) {
    __syncthreads();
#pragma unroll
    for (int it = 0; it < 4; ++it)
      async_cp16(Ab + (size_t)srow[it] * K + k0 + sgcb[it] * 8,
                 &As[it * 2048 + ldsbase]);
#pragma unroll
    for (int it = 0; it < 4; ++it)
      async_cp16(Bb + (size_t)srow[it] * K + k0 + sgcb[it] * 8,
                 &Bs[it * 2048 + ldsbase]);
    __syncthreads();
#pragma unroll
    for (int kk = 0; kk < 2; ++kk) {
      bf16x8 a[4], b[4];
#pragma unroll
      for (int i = 0; i < 4; ++i) {
        int rr = wm * 64 + i * 16 + m16;
        int cb = (kk << 2) + quad;
        a[i] = *reinterpret_cast<const bf16x8*>(
            &As[rr * BK + ((cb ^ (rr & 7)) << 3)]);
      }
#pragma unroll
      for (int j = 0; j < 4; ++j) {
        int rr = wn * 64 + j * 16 + m16;
        int cb = (kk << 2) + quad;
        b[j] = *reinterpret_cast<const bf16x8*>(
            &Bs[rr * BK + ((cb ^ (rr & 7)) << 3)]);
      }
#pragma unroll
      for (int i = 0; i < 4; ++i)
#pragma unroll
        for (int j = 0; j < 4; ++j)
          acc[i][j] =
              __builtin_amdgcn_mfma_f32_16x16x32_bf16(a[i], b[j], acc[i][j], 0, 0, 0);
    }
  }

  int rowB = tm * BM + wm * 64;
  int colB = tn * BN + wn * 64;
  if constexpr (EPI == 1) {
#pragma unroll
    for (int i = 0; i < 4; ++i)
#pragma unroll
      for (int j = 0; j < 4; ++j) {
        int col = colB + j * 16 + m16;
        int row0 = rowB + i * 16 + quad * 4;
#pragma unroll
        for (int t = 0; t < 4; ++t)
          atomicAdd(&C[(size_t)(row0 + t) * N + col], acc[i][j][t]);
      }
  } else {  // EPI == 4: bias + softplus -> bf16
#pragma unroll
    for (int i = 0; i < 4; ++i)
#pragma unroll
      for (int j = 0; j < 4; ++j) {
        int col = colB + j * 16 + m16;
        float bv = bias[col];
        int row0 = rowB + i * 16 + quad * 4;
#pragma unroll
        for (int t = 0; t < 4; ++t) {
          float x = acc[i][j][t] + bv;
          auxB[(size_t)(row0 + t) * EE + col] = f2bf(softplus_fast(x));
        }
      }
  }
}

// ------------- direct (no-LDS) BT-GEMM for skinny N (x_proj) -------------
__global__ __launch_bounds__(256) void gemm_bt(
    const unsigned short* __restrict__ A,
    const unsigned short* __restrict__ B,
    float* __restrict__ C,
    int M, int N, int K, int tilesN, int splitk) {
  int bid = blockIdx.x;
  int groupSize = 8 * tilesN;
  int g = bid / groupSize, r = bid % groupSize;
  int tm = g * 8 + (r & 7);
  int tn = r >> 3;

  int Kslice = K / splitk;
  int k_begin = blockIdx.y * Kslice;
  int k_end = k_begin + Kslice;

  int tid = threadIdx.x;
  int wave = tid >> 6, lane = tid & 63;
  int wm = wave & 1, wn = wave >> 1;
  int m16 = lane & 15, quad = lane >> 4;
  int rowBase = tm * 64 + wm * 32;
  int colBase = tn * 128 + wn * 64;

  const unsigned short* a0p = A + (size_t)(rowBase + m16) * K + quad * 8;
  const unsigned short* a1p = A + (size_t)(rowBase + 16 + m16) * K + quad * 8;
  const unsigned short* bp[4];
  bool bok[4];
#pragma unroll
  for (int j = 0; j < 4; ++j) {
    int col = colBase + j * 16 + m16;
    bok[j] = (col < N);
    bp[j] = B + (size_t)(bok[j] ? col : 0) * K + quad * 8;
  }

  f32x4 acc[2][4];
#pragma unroll
  for (int i = 0; i < 2; ++i)
#pragma unroll
    for (int j = 0; j < 4; ++j)
#pragma unroll
      for (int t = 0; t < 4; ++t) acc[i][j][t] = 0.0f;

  bf16x8 zero8;
#pragma unroll
  for (int t = 0; t < 8; ++t) zero8[t] = (__bf16)0.0f;

  for (int k = k_begin; k < k_end; k += 32) {
    bf16x8 a0 = *reinterpret_cast<const bf16x8*>(a0p + k);
    bf16x8 a1 = *reinterpret_cast<const bf16x8*>(a1p + k);
    bf16x8 b[4];
#pragma unroll
    for (int j = 0; j < 4; ++j)
      b[j] = bok[j] ? *reinterpret_cast<const bf16x8*>(bp[j] + k) : zero8;
#pragma unroll
    for (int j = 0; j < 4; ++j) {
      acc[0][j] = __builtin_amdgcn_mfma_f32_16x16x32_bf16(a0, b[j], acc[0][j], 0, 0, 0);
      acc[1][j] = __builtin_amdgcn_mfma_f32_16x16x32_bf16(a1, b[j], acc[1][j], 0, 0, 0);
    }
  }

#pragma unroll
  for (int i = 0; i < 2; ++i)
#pragma unroll
    for (int j = 0; j < 4; ++j) {
      int col = colBase + j * 16 + m16;
      if (col >= N) continue;
      int row0 = rowBase + i * 16 + quad * 4;
      if (splitk == 1) {
#pragma unroll
        for (int t = 0; t < 4; ++t)
          C[(size_t)(row0 + t) * N + col] = acc[i][j][t];
      } else {
#pragma unroll
        for (int t = 0; t < 4; ++t)
          atomicAdd(&C[(size_t)(row0 + t) * N + col], acc[i][j][t]);
      }
    }
}

// ------- depthwise causal conv (K=4) + bias + silu, register window -------
__global__ __launch_bounds__(256) void conv_silu_k(
    const float* __restrict__ projh, const float* __restrict__ cw,
    const float* __restrict__ cb, unsigned short* __restrict__ hb) {
  int e = blockIdx.x * 256 + threadIdx.x;
  int l0 = blockIdx.y * 16;
  float w0 = cw[e * 4 + 0], w1 = cw[e * 4 + 1];
  float w2 = cw[e * 4 + 2], w3 = cw[e * 4 + 3];
  float bias = cb[e];
  float xm3 = (l0 >= 3) ? projh[(size_t)(l0 - 3) * EE + e] : 0.0f;
  float xm2 = (l0 >= 2) ? projh[(size_t)(l0 - 2) * EE + e] : 0.0f;
  float xm1 = (l0 >= 1) ? projh[(size_t)(l0 - 1) * EE + e] : 0.0f;
#pragma unroll
  for (int t = 0; t < 16; ++t) {
    int l = l0 + t;
    float x0 = projh[(size_t)l * EE + e];
    float acc = bias + w0 * xm3 + w1 * xm2 + w2 * xm1 + w3 * x0;
    float s = acc / (1.0f + __expf(-acc));
    hb[(size_t)l * EE + e] = f2bf(s);
    xm3 = xm2; xm2 = xm1; xm1 = x0;
  }
}

// ---------------- extract dt rows of ssm -> bf16 [L,128] ----------------
__global__ void dtcast_k(const float* __restrict__ ssm,
                         unsigned short* __restrict__ dtin, int n) {
  int i = blockIdx.x * blockDim.x + threadIdx.x;
  if (i >= n) return;
  int l = i >> 7, r = i & 127;
  dtin[i] = f2bf(ssm[l * 160 + r]);
}

// ================= chunked selective scan (16 states per thread) ===========
__global__ __launch_bounds__(256) void scan_partA(
    const unsigned short* __restrict__ dtb, const unsigned short* __restrict__ hb,
    const float* __restrict__ ssm, const float* __restrict__ A_log,
    float* __restrict__ P, float* __restrict__ S) {
  int e = blockIdx.y * 256 + threadIdx.x;
  int c = blockIdx.x;
  float Aa[16];
#pragma unroll
  for (int q = 0; q < 4; ++q) {
    float4 a = reinterpret_cast<const float4*>(&A_log[(size_t)e * NS])[q];
    Aa[q * 4 + 0] = -__expf(a.x) * 1.44269504f;
    Aa[q * 4 + 1] = -__expf(a.y) * 1.44269504f;
    Aa[q * 4 + 2] = -__expf(a.z) * 1.44269504f;
    Aa[q * 4 + 3] = -__expf(a.w) * 1.44269504f;
  }
  float s[16], p[16];
#pragma unroll
  for (int n = 0; n < 16; ++n) { s[n] = 0.0f; p[n] = 1.0f; }
  int l0 = c * CT;
#pragma unroll 2
  for (int t = 0; t < CT; ++t) {
    int l = l0 + t;
    size_t o = (size_t)l * EE + e;
    float dtv = bf2f(dtb[o]);
    float hv = bf2f(hb[o]);
    float Bv[16];
#pragma unroll
    for (int q = 0; q < 4; ++q)
      *reinterpret_cast<float4*>(&Bv[q * 4]) =
          reinterpret_cast<const float4*>(&ssm[(size_t)l * 160 + 128])[q];
    float z = dtv * hv;
#pragma unroll
    for (int n = 0; n < 16; ++n) {
      float dA = __builtin_amdgcn_exp2f(dtv * Aa[n]);
      s[n] = s[n] * dA + z * Bv[n];
      p[n] *= dA;
    }
  }
  size_t base = ((size_t)c * EE + e) * NS;
#pragma unroll
  for (int q = 0; q < 4; ++q) {
    reinterpret_cast<float4*>(&P[base])[q] = *reinterpret_cast<float4*>(&p[q * 4]);
    reinterpret_cast<float4*>(&S[base])[q] = *reinterpret_cast<float4*>(&s[q * 4]);
  }
}

__global__ __launch_bounds__(256) void scan_chunkB(
    const float* __restrict__ P, float* __restrict__ S) {
  int gidx = blockIdx.x * 256 + threadIdx.x;
  float s = 0.0f;
  float pv = P[gidx], sv = S[gidx];
  for (int c = 0; c < NC; ++c) {
    float pn = 0.0f, sn = 0.0f;
    if (c + 1 < NC) {
      size_t i2 = (size_t)(c + 1) * (EE * NS) + gidx;
      pn = P[i2];
      sn = S[i2];
    }
    float s_next = s * pv + sv;
    S[(size_t)c * (EE * NS) + gidx] = s;
    s = s_next;
    pv = pn; sv = sn;
  }
}

__global__ __launch_bounds__(256) void scan_partC(
    const unsigned short* __restrict__ dtb, const unsigned short* __restrict__ hb,
    const float* __restrict__ ssm, const float* __restrict__ A_log,
    const float* __restrict__ Dp, const unsigned short* __restrict__ sg,
    const float* __restrict__ Sinit, unsigned short* __restrict__ yb) {
  int e = blockIdx.y * 256 + threadIdx.x;
  int c = blockIdx.x;
  float Aa[16];
#pragma unroll
  for (int q = 0; q < 4; ++q) {
    float4 a = reinterpret_cast<const float4*>(&A_log[(size_t)e * NS])[q];
    Aa[q * 4 + 0] = -__expf(a.x) * 1.44269504f;
    Aa[q * 4 + 1] = -__expf(a.y) * 1.44269504f;
    Aa[q * 4 + 2] = -__expf(a.z) * 1.44269504f;
    Aa[q * 4 + 3] = -__expf(a.w) * 1.44269504f;
  }
  float Dv = Dp[e];
  float s[16];
  size_t base = ((size_t)c * EE + e) * NS;
#pragma unroll
  for (int q = 0; q < 4; ++q)
    *reinterpret_cast<float4*>(&s[q * 4]) =
        reinterpret_cast<const float4*>(&Sinit[base])[q];
  int l0 = c * CT;
#pragma unroll 2
  for (int t = 0; t < CT; ++t) {
    int l = l0 + t;
    size_t o = (size_t)l * EE + e;
    float dtv = bf2f(dtb[o]);
    float hv = bf2f(hb[o]);
    float Bv[16], Cv[16];
#pragma unroll
    for (int q = 0; q < 4; ++q) {
      *reinterpret_cast<float4*>(&Bv[q * 4]) =
          reinterpret_cast<const float4*>(&ssm[(size_t)l * 160 + 128])[q];
      *reinterpret_cast<float4*>(&Cv[q * 4]) =
          reinterpret_cast<const float4*>(&ssm[(size_t)l * 160 + 144])[q];
    }
    float z = dtv * hv;
    float y = 0.0f;
#pragma unroll
    for (int n = 0; n < 16; ++n) {
      float dA = __builtin_amdgcn_exp2f(dtv * Aa[n]);
      s[n] = s[n] * dA + z * Bv[n];
      y += s[n] * Cv[n];
    }
    float gv = bf2f(sg[o]);  // pre-activated silu(gate)
    float yv = (y + hv * Dv) * gv;
    yb[o] = f2bf(yv);
  }
}

extern "C" void kernel_launch(void* const* d_in, const int* in_sizes, int n_in,
                              void* d_out, int out_size, void* d_ws, size_t ws_size,
                              hipStream_t stream) {
  const float* hs   = (const float*)d_in[0];
  const float* w1   = (const float*)d_in[1];
  const float* cw   = (const float*)d_in[2];
  const float* cb   = (const float*)d_in[3];
  const float* xw   = (const float*)d_in[4];
  const float* dtw  = (const float*)d_in[5];
  const float* dtb  = (const float*)d_in[6];
  const float* Alog = (const float*)d_in[7];
  const float* Dp   = (const float*)d_in[8];
  const float* ow   = (const float*)d_in[9];
  float* out = (float*)d_out;

  char* ws = (char*)d_ws;
  size_t off = 0;
  auto alloc = [&](size_t b) {
    char* p = ws + off;
    off += (b + 255) & ~(size_t)255;
    return p;
  };
  float* projh = (float*)alloc((size_t)LL * EE * 4);                 // 33.5 MB
  unsigned short* sg  = (unsigned short*)alloc((size_t)LL * EE * 2); // 16.8 MB
  unsigned short* hb  = (unsigned short*)alloc((size_t)LL * EE * 2); // 16.8 MB
  unsigned short* dtb_buf = (unsigned short*)alloc((size_t)LL * EE * 2); // 16.8 MB
  unsigned short* w1b = (unsigned short*)alloc((size_t)2 * EE * HH * 2); // 33.5 MB
  unsigned short* hsb = (unsigned short*)alloc((size_t)LL * HH * 2);
  unsigned short* yb  = (unsigned short*)alloc((size_t)LL * EE * 2);
  unsigned short* owb = (unsigned short*)alloc((size_t)HH * EE * 2);
  unsigned short* xwb = (unsigned short*)alloc((size_t)160 * EE * 2);
  float* ssm = (float*)alloc((size_t)LL * 160 * 4);
  unsigned short* dtin = (unsigned short*)alloc((size_t)LL * RR * 2);
  unsigned short* dtwb = (unsigned short*)alloc((size_t)EE * RR * 2);
  float* Pbuf = (float*)alloc((size_t)NC * EE * NS * 4);             // 16.8 MB
  float* Sbuf = (float*)alloc((size_t)NC * EE * NS * 4);             // 16.8 MB

  // 0) fused prep: all input casts + zero fills in ONE launch
  prep_k<<<P_C6 / 256, 256, 0, stream>>>(hs, hsb, w1, w1b, xw, xwb, dtw, dtwb,
                                         ow, owb, ssm, out);

  // 1) proj = hs @ in_proj_w^T [2048, 8192]; 256^2 8-phase counted-vmcnt.
  //    epilogue: h -> projh f32, gate -> silu -> sg bf16
  {
    int tilesM = LL / 256;          // 8
    int tilesN = (2 * EE) / 256;    // 32  -> 256 blocks, 1/CU
    gemm256<2><<<dim3(tilesM * tilesN, 1), 512, 0, stream>>>(
        hsb, w1b, nullptr, LL, 2 * EE, HH, tilesM, 1, projh, sg);
  }
  // 2) causal depthwise conv + silu -> h (bf16)
  conv_silu_k<<<dim3(EE / 256, LL / 16), 256, 0, stream>>>(projh, cw, cb, hb);
  // 3) ssm = h @ x_proj_w^T [2048, 160] k=4096, split-K=8 (skinny N)
  {
    int tilesN = (160 + 127) / 128, tilesM = LL / 64;
    gemm_bt<<<dim3(tilesM * tilesN, 8), 256, 0, stream>>>(
        hb, xwb, ssm, LL, 160, EE, tilesN, 8);
  }
  // 4) dt input slice -> bf16
  dtcast_k<<<(LL * RR + 255) / 256, 256, 0, stream>>>(ssm, dtin, LL * RR);
  // 5) dt = softplus(dtin @ dt_proj_w^T + dtb) -> bf16   [2048, 4096] k=128
  {
    int tilesN = EE / BN, tilesM = LL / BM;
    gemm_lds_t<4><<<dim3(tilesM * tilesN, 1), 256, 0, stream>>>(
        dtin, dtwb, nullptr, LL, EE, RR, tilesM, 1, dtb, nullptr, dtb_buf);
  }
  // 6) chunked selective scan + gating -> y (bf16)
  scan_partA<<<dim3(NC, EE / 256), 256, 0, stream>>>(dtb_buf, hb, ssm, Alog,
                                                     Pbuf, Sbuf);
  scan_chunkB<<<EE * NS / 256, 256, 0, stream>>>(Pbuf, Sbuf);
  scan_partC<<<dim3(NC, EE / 256), 256, 0, stream>>>(dtb_buf, hb, ssm, Alog, Dp,
                                                     sg, Sbuf, yb);
  // 7) out = y @ out_proj_w^T [2048, 2048] k=4096; 256^2 8-phase pipeline,
  //    split-K=4 (NT=16 even) -> 256 blocks, f32 atomicAdd epilogue
  {
    int tilesM = LL / 256, tilesN = HH / 256;  // 8 x 8
    gemm256<1><<<dim3(tilesM * tilesN, 4), 512, 0, stream>>>(
        yb, owb, out, LL, HH, EE, tilesM, 4, nullptr, nullptr);
  }
}

// Round 5
// 416.157 us; speedup vs baseline: 1.0465x; 1.0465x over previous
//
#include <hip/hip_runtime.h>

#define LL 2048
#define HH 2048
#define EE 4096
#define NS 16
#define RR 128
#define CT 32            // chunk timesteps
#define NC (LL / CT)     // 64 chunks
#define BM 128
#define BN 128
#define BK 64

typedef __bf16 bf16x8 __attribute__((ext_vector_type(8)));
typedef float f32x4 __attribute__((ext_vector_type(4)));

__device__ __forceinline__ unsigned short f2bf(float f) {
  union { float f; unsigned int u; } v; v.f = f;
  unsigned int r = v.u + 0x7fffu + ((v.u >> 16) & 1u);
  return (unsigned short)(r >> 16);
}

__device__ __forceinline__ float bf2f(unsigned short u) {
  union { unsigned int i; float f; } v;
  v.i = ((unsigned int)u) << 16;
  return v.f;
}

// softplus via native transcendentals only (NO libm log1pf — it's a non-inline
// ocml call that forces VGPR save/restore in high-pressure epilogues)
__device__ __forceinline__ float softplus_fast(float x) {
  if (x > 20.0f) return x;
  float e = __builtin_amdgcn_exp2f(1.44269504f * x);
  return 0.69314718f * __builtin_amdgcn_logf(1.0f + e);
}

__device__ __forceinline__ void async_cp16(const unsigned short* g,
                                           unsigned short* l) {
  __builtin_amdgcn_global_load_lds(
      (const __attribute__((address_space(1))) unsigned int*)g,
      (__attribute__((address_space(3))) unsigned int*)l, 16, 0, 0);
}

// ============ fused prep: 5 bf16 casts + 2 zero fills, ONE launch ==========
// All boundaries are multiples of 256 (whole blocks per segment -> no
// divergence). float4/ushort4 vectorized.
#define P_C0 (LL * HH / 4)               // hs -> hsb        1048576
#define P_C1 (P_C0 + 2 * EE * HH / 4)    // w1 -> w1b        5242880
#define P_C2 (P_C1 + 160 * EE / 4)       // xw -> xwb        5406720
#define P_C3 (P_C2 + EE * RR / 4)        // dtw -> dtwb      5537792
#define P_C4 (P_C3 + HH * EE / 4)        // ow -> owb        7634944
#define P_C5 (P_C4 + LL * 160 / 4)       // zero ssm         7716864
#define P_C6 (P_C5 + LL * HH / 4)        // zero out         8765440

__global__ __launch_bounds__(256) void prep_k(
    const float* __restrict__ hs, unsigned short* __restrict__ hsb,
    const float* __restrict__ w1, unsigned short* __restrict__ w1b,
    const float* __restrict__ xw, unsigned short* __restrict__ xwb,
    const float* __restrict__ dtw, unsigned short* __restrict__ dtwb,
    const float* __restrict__ ow, unsigned short* __restrict__ owb,
    float* __restrict__ ssm, float* __restrict__ out) {
  int i = blockIdx.x * 256 + threadIdx.x;
  const float* src = nullptr;
  unsigned short* dst = nullptr;
  int k = 0;
  if (i < P_C0)      { src = hs;  dst = hsb;  k = i; }
  else if (i < P_C1) { src = w1;  dst = w1b;  k = i - P_C0; }
  else if (i < P_C2) { src = xw;  dst = xwb;  k = i - P_C1; }
  else if (i < P_C3) { src = dtw; dst = dtwb; k = i - P_C2; }
  else if (i < P_C4) { src = ow;  dst = owb;  k = i - P_C3; }
  else if (i < P_C5) {
    float4 z; z.x = z.y = z.z = z.w = 0.0f;
    reinterpret_cast<float4*>(ssm)[i - P_C4] = z;
    return;
  } else {
    float4 z; z.x = z.y = z.z = z.w = 0.0f;
    reinterpret_cast<float4*>(out)[i - P_C5] = z;
    return;
  }
  float4 v = reinterpret_cast<const float4*>(src)[k];
  ushort4 o;
  o.x = f2bf(v.x); o.y = f2bf(v.y); o.z = f2bf(v.z); o.w = f2bf(v.w);
  reinterpret_cast<ushort4*>(dst)[k] = o;
}

// ============= 256x256 8-phase BT-GEMM (faithful m201-style) ===============
// C[M,N] = A[M,K] * B[N,K]^T, bf16 in / f32 acc. 512 threads = 8 waves (2Mx4N),
// per-wave 128x64 output. BK=64, double-buffered LDS (128 KiB): buf0 = even
// K-tiles, buf1 = odd. Iteration = 2 K-tiles (t0 even, t1=t0+1), 8 phases.
// Each phase: {ds_read subtile; stage 1 half-tile into DEAD region; barrier;
// lgkm0; setprio1; 16 MFMA (kk-outer -> dep distance 8); setprio0; barrier}.
// Counted waits ONLY (never drain in steady state):
//   end p3: vmcnt(4)   end p7: vmcnt(6)
// Stage slots: p0: A(t1)h1 | p2: B(t0+2)h0 | p3: B(t0+2)h1 | p4: A(t0+2)h0
//   p5: A(t0+2)h1 | p6: B(t1+2)h0 | p7: B(t1+2)h1 + A(t1+2)h0
// LDS swizzle: 16B-block XOR by row&7, both-sides. SQ_LDS_BANK_CONFLICT=0.
// Measured (R3): in_proj 77.8us, MfmaUtil 37%, FETCH 49MB.
// NOTE: EPI=1 atomic split-K epilogue on this kernel measured ~95us for
// out_proj (cross-XCD atomic RMW serialization) — do NOT use for split-K.
// EPI: 2 = in_proj (cols<EE -> f32 auxF; cols>=EE -> silu bf16 auxB)
template <int EPI>
__global__ __launch_bounds__(512, 2) void gemm256(
    const unsigned short* __restrict__ A,
    const unsigned short* __restrict__ B,
    float* __restrict__ C,
    int M, int N, int K, int tilesM, int splitk,
    float* __restrict__ auxF, unsigned short* __restrict__ auxB) {
  __shared__ __align__(16) unsigned short As[2][16384];
  __shared__ __align__(16) unsigned short Bs[2][16384];

  int bid = blockIdx.x;
  int tnInner = bid & 7;             // XCD-locality
  int rest = bid >> 3;
  int tm = rest % tilesM;
  int tn = (rest / tilesM) * 8 + tnInner;

  int Kslice = K / splitk;
  int k_begin = blockIdx.y * Kslice;
  int NT = Kslice / 64;              // even, >= 2

  int tid = threadIdx.x;
  int lane = tid & 63;
  int wave = tid >> 6;               // 0..7
  int wm = wave >> 2;                // 0..1
  int wn = wave & 3;                 // 0..3
  int m16 = lane & 15, quad = lane >> 4;

  const unsigned short* Ab = A + (size_t)tm * 256 * K;
  const unsigned short* Bb = B + (size_t)tn * 256 * K;

  // staging geometry: one call = 512 threads x 16B = 64 rows x 64 cols
  int rowS = tid >> 3;
  int gcbS = (tid & 7) ^ (rowS & 7);
  int ldsWB = (tid & ~63) * 8;

  // ds_read fragment addressing (ushort offsets)
  int sw = m16 & 7;
  int coff0 = (quad ^ sw) << 3;
  int coff1 = ((4 + quad) ^ sw) << 3;
  int aoff = (wm * 128 + m16) * 64;
  int boff = (wn * 64 + m16) * 64;

  f32x4 acc[8][4];
#pragma unroll
  for (int i = 0; i < 8; ++i)
#pragma unroll
    for (int j = 0; j < 4; ++j)
#pragma unroll
      for (int t = 0; t < 4; ++t) acc[i][j][t] = 0.0f;

  // half-tile stagers: h in {0,1} -> chunks {2h, 2h+1}
  auto stageA = [&](int bufb, int t, int h) {
    int kt = k_begin + t * 64;
    unsigned short* dst = &As[bufb][0];
#pragma unroll
    for (int c = 2 * h; c < 2 * h + 2; ++c)
      async_cp16(Ab + (size_t)(c * 64 + rowS) * K + kt + gcbS * 8,
                 dst + c * 4096 + ldsWB);
  };
  auto stageB = [&](int bufb, int t, int h) {
    int kt = k_begin + t * 64;
    unsigned short* dst = &Bs[bufb][0];
#pragma unroll
    for (int c = 2 * h; c < 2 * h + 2; ++c)
      async_cp16(Bb + (size_t)(c * 64 + rowS) * K + kt + gcbS * 8,
                 dst + c * 4096 + ldsWB);
  };

  // ---- prologue: tile0 full (8), then B(1)h0,h1 + A(1)h0 (6); vmcnt(6) ----
  stageA(0, 0, 0); stageA(0, 0, 1);
  stageB(0, 0, 0); stageB(0, 0, 1);
  stageB(1, 1, 0); stageB(1, 1, 1);
  stageA(1, 1, 0);
  asm volatile("s_waitcnt vmcnt(6)" ::: "memory");
  __builtin_amdgcn_s_barrier();

  bf16x8 a[4][2], b0[2][2], b1[2][2];

  for (int t0 = 0; t0 < NT; t0 += 2) {
    int t1 = t0 + 1;
    bool notLast = (t0 + 2 < NT);
    unsigned short* A0 = &As[0][0];
    unsigned short* B0 = &Bs[0][0];
    unsigned short* A1 = &As[1][0];
    unsigned short* B1 = &Bs[1][0];

    // ================= K-tile t0 (buf0), phases p0..p3 =================
    // ---- p0: reads a-lo + b0; stage A(t1)h1; MFMA q00 ----
#pragma unroll
    for (int i = 0; i < 4; ++i) {
      a[i][0] = *reinterpret_cast<const bf16x8*>(&A0[aoff + i * 1024 + coff0]);
      a[i][1] = *reinterpret_cast<const bf16x8*>(&A0[aoff + i * 1024 + coff1]);
    }
#pragma unroll
    for (int j = 0; j < 2; ++j) {
      b0[j][0] = *reinterpret_cast<const bf16x8*>(&B0[boff + j * 1024 + coff0]);
      b0[j][1] = *reinterpret_cast<const bf16x8*>(&B0[boff + j * 1024 + coff1]);
    }
    stageA(1, t1, 1);
    __builtin_amdgcn_s_barrier();
    asm volatile("s_waitcnt lgkmcnt(0)" ::: "memory");
    __builtin_amdgcn_sched_barrier(0);
    __builtin_amdgcn_s_setprio(1);
#pragma unroll
    for (int kk = 0; kk < 2; ++kk)
#pragma unroll
      for (int i = 0; i < 4; ++i)
#pragma unroll
        for (int j = 0; j < 2; ++j)
          acc[i][j] = __builtin_amdgcn_mfma_f32_16x16x32_bf16(
              a[i][kk], b0[j][kk], acc[i][j], 0, 0, 0);
    __builtin_amdgcn_s_setprio(0);
    __builtin_amdgcn_s_barrier();

    // ---- p1: reads b1; MFMA q01 ----
#pragma unroll
    for (int j = 0; j < 2; ++j) {
      b1[j][0] = *reinterpret_cast<const bf16x8*>(&B0[boff + (2 + j) * 1024 + coff0]);
      b1[j][1] = *reinterpret_cast<const bf16x8*>(&B0[boff + (2 + j) * 1024 + coff1]);
    }
    __builtin_amdgcn_s_barrier();
    asm volatile("s_waitcnt lgkmcnt(0)" ::: "memory");
    __builtin_amdgcn_sched_barrier(0);
    __builtin_amdgcn_s_setprio(1);
#pragma unroll
    for (int kk = 0; kk < 2; ++kk)
#pragma unroll
      for (int i = 0; i < 4; ++i)
#pragma unroll
        for (int j = 0; j < 2; ++j)
          acc[i][2 + j] = __builtin_amdgcn_mfma_f32_16x16x32_bf16(
              a[i][kk], b1[j][kk], acc[i][2 + j], 0, 0, 0);
    __builtin_amdgcn_s_setprio(0);
    __builtin_amdgcn_s_barrier();

    // ---- p2: reads a-hi; stage B(t0+2)h0 (B-buf0 dead); MFMA q11 ----
#pragma unroll
    for (int i = 0; i < 4; ++i) {
      a[i][0] = *reinterpret_cast<const bf16x8*>(&A0[aoff + (4 + i) * 1024 + coff0]);
      a[i][1] = *reinterpret_cast<const bf16x8*>(&A0[aoff + (4 + i) * 1024 + coff1]);
    }
    if (notLast) stageB(0, t0 + 2, 0);
    __builtin_amdgcn_s_barrier();
    asm volatile("s_waitcnt lgkmcnt(0)" ::: "memory");
    __builtin_amdgcn_sched_barrier(0);
    __builtin_amdgcn_s_setprio(1);
#pragma unroll
    for (int kk = 0; kk < 2; ++kk)
#pragma unroll
      for (int i = 0; i < 4; ++i)
#pragma unroll
        for (int j = 0; j < 2; ++j)
          acc[4 + i][2 + j] = __builtin_amdgcn_mfma_f32_16x16x32_bf16(
              a[i][kk], b1[j][kk], acc[4 + i][2 + j], 0, 0, 0);
    __builtin_amdgcn_s_setprio(0);
    __builtin_amdgcn_s_barrier();

    // ---- p3: no reads (b0 in regs); stage B(t0+2)h1; MFMA q10; vmcnt(4) ----
    if (notLast) stageB(0, t0 + 2, 1);
    __builtin_amdgcn_s_setprio(1);
#pragma unroll
    for (int kk = 0; kk < 2; ++kk)
#pragma unroll
      for (int i = 0; i < 4; ++i)
#pragma unroll
        for (int j = 0; j < 2; ++j)
          acc[4 + i][j] = __builtin_amdgcn_mfma_f32_16x16x32_bf16(
              a[i][kk], b0[j][kk], acc[4 + i][j], 0, 0, 0);
    __builtin_amdgcn_s_setprio(0);
    if (notLast) {
      asm volatile("s_waitcnt vmcnt(4)" ::: "memory");
    } else {
      asm volatile("s_waitcnt vmcnt(0)" ::: "memory");
    }
    __builtin_amdgcn_s_barrier();

    // ================= K-tile t1 (buf1), phases p4..p7 =================
    // ---- p4: reads a-lo + b0; stage A(t0+2)h0 (A-buf0 dead); MFMA q00 ----
#pragma unroll
    for (int i = 0; i < 4; ++i) {
      a[i][0] = *reinterpret_cast<const bf16x8*>(&A1[aoff + i * 1024 + coff0]);
      a[i][1] = *reinterpret_cast<const bf16x8*>(&A1[aoff + i * 1024 + coff1]);
    }
#pragma unroll
    for (int j = 0; j < 2; ++j) {
      b0[j][0] = *reinterpret_cast<const bf16x8*>(&B1[boff + j * 1024 + coff0]);
      b0[j][1] = *reinterpret_cast<const bf16x8*>(&B1[boff + j * 1024 + coff1]);
    }
    if (notLast) stageA(0, t0 + 2, 0);
    __builtin_amdgcn_s_barrier();
    asm volatile("s_waitcnt lgkmcnt(0)" ::: "memory");
    __builtin_amdgcn_sched_barrier(0);
    __builtin_amdgcn_s_setprio(1);
#pragma unroll
    for (int kk = 0; kk < 2; ++kk)
#pragma unroll
      for (int i = 0; i < 4; ++i)
#pragma unroll
        for (int j = 0; j < 2; ++j)
          acc[i][j] = __builtin_amdgcn_mfma_f32_16x16x32_bf16(
              a[i][kk], b0[j][kk], acc[i][j], 0, 0, 0);
    __builtin_amdgcn_s_setprio(0);
    __builtin_amdgcn_s_barrier();

    // ---- p5: reads b1; stage A(t0+2)h1; MFMA q01 ----
#pragma unroll
    for (int j = 0; j < 2; ++j) {
      b1[j][0] = *reinterpret_cast<const bf16x8*>(&B1[boff + (2 + j) * 1024 + coff0]);
      b1[j][1] = *reinterpret_cast<const bf16x8*>(&B1[boff + (2 + j) * 1024 + coff1]);
    }
    if (notLast) stageA(0, t0 + 2, 1);
    __builtin_amdgcn_s_barrier();
    asm volatile("s_waitcnt lgkmcnt(0)" ::: "memory");
    __builtin_amdgcn_sched_barrier(0);
    __builtin_amdgcn_s_setprio(1);
#pragma unroll
    for (int kk = 0; kk < 2; ++kk)
#pragma unroll
      for (int i = 0; i < 4; ++i)
#pragma unroll
        for (int j = 0; j < 2; ++j)
          acc[i][2 + j] = __builtin_amdgcn_mfma_f32_16x16x32_bf16(
              a[i][kk], b1[j][kk], acc[i][2 + j], 0, 0, 0);
    __builtin_amdgcn_s_setprio(0);
    __builtin_amdgcn_s_barrier();

    // ---- p6: reads a-hi; stage B(t1+2)h0; MFMA q11 ----
#pragma unroll
    for (int i = 0; i < 4; ++i) {
      a[i][0] = *reinterpret_cast<const bf16x8*>(&A1[aoff + (4 + i) * 1024 + coff0]);
      a[i][1] = *reinterpret_cast<const bf16x8*>(&A1[aoff + (4 + i) * 1024 + coff1]);
    }
    if (notLast) stageB(1, t1 + 2, 0);
    __builtin_amdgcn_s_barrier();
    asm volatile("s_waitcnt lgkmcnt(0)" ::: "memory");
    __builtin_amdgcn_sched_barrier(0);
    __builtin_amdgcn_s_setprio(1);
#pragma unroll
    for (int kk = 0; kk < 2; ++kk)
#pragma unroll
      for (int i = 0; i < 4; ++i)
#pragma unroll
        for (int j = 0; j < 2; ++j)
          acc[4 + i][2 + j] = __builtin_amdgcn_mfma_f32_16x16x32_bf16(
              a[i][kk], b1[j][kk], acc[4 + i][2 + j], 0, 0, 0);
    __builtin_amdgcn_s_setprio(0);
    __builtin_amdgcn_s_barrier();

    // ---- p7: no reads; stage B(t1+2)h1 + A(t1+2)h0; MFMA q10; vmcnt(6) ----
    if (notLast) { stageB(1, t1 + 2, 1); stageA(1, t1 + 2, 0); }
    __builtin_amdgcn_s_setprio(1);
#pragma unroll
    for (int kk = 0; kk < 2; ++kk)
#pragma unroll
      for (int i = 0; i < 4; ++i)
#pragma unroll
        for (int j = 0; j < 2; ++j)
          acc[4 + i][j] = __builtin_amdgcn_mfma_f32_16x16x32_bf16(
              a[i][kk], b0[j][kk], acc[4 + i][j], 0, 0, 0);
    __builtin_amdgcn_s_setprio(0);
    if (notLast) {
      asm volatile("s_waitcnt vmcnt(6)" ::: "memory");
    }
    __builtin_amdgcn_s_barrier();
  }

  // ---------------- epilogue ----------------
  int rowB = tm * 256 + wm * 128;
  int colB = tn * 256 + wn * 64;
  if constexpr (EPI == 1) {
#pragma unroll
    for (int mi = 0; mi < 8; ++mi)
#pragma unroll
      for (int nj = 0; nj < 4; ++nj) {
        int col = colB + nj * 16 + m16;
        int row0 = rowB + mi * 16 + quad * 4;
#pragma unroll
        for (int t4 = 0; t4 < 4; ++t4)
          atomicAdd(&C[(size_t)(row0 + t4) * N + col], acc[mi][nj][t4]);
      }
  } else {  // EPI == 2: in_proj epilogue
    if (colB < EE) {
#pragma unroll
      for (int mi = 0; mi < 8; ++mi)
#pragma unroll
        for (int nj = 0; nj < 4; ++nj) {
          int col = colB + nj * 16 + m16;
          int row0 = rowB + mi * 16 + quad * 4;
#pragma unroll
          for (int t4 = 0; t4 < 4; ++t4)
            auxF[(size_t)(row0 + t4) * EE + col] = acc[mi][nj][t4];
        }
    } else {
#pragma unroll
      for (int mi = 0; mi < 8; ++mi)
#pragma unroll
        for (int nj = 0; nj < 4; ++nj) {
          int cg = colB + nj * 16 + m16 - EE;
          int row0 = rowB + mi * 16 + quad * 4;
#pragma unroll
          for (int t4 = 0; t4 < 4; ++t4) {
            float v = acc[mi][nj][t4];
            float s = v / (1.0f + __expf(-v));
            auxB[(size_t)(row0 + t4) * EE + cg] = f2bf(s);
          }
        }
    }
  }
}

// ============ LDS-staged bf16 BT-GEMM (128x128) — out_proj & dt_proj =======
// EPI: 1 = f32 atomicAdd (split-K)   4 = +bias[col], softplus, bf16 to auxB
template <int EPI>
__global__ __launch_bounds__(256) void gemm_lds_t(
    const unsigned short* __restrict__ A,
    const unsigned short* __restrict__ B,
    float* __restrict__ C,
    int M, int N, int K, int tilesM, int splitk,
    const float* __restrict__ bias, float* __restrict__ auxF,
    unsigned short* __restrict__ auxB) {
  __shared__ __align__(16) unsigned short As[BM * BK];
  __shared__ __align__(16) unsigned short Bs[BN * BK];

  int bid = blockIdx.x;
  int tnInner = bid & 7;
  int rest = bid >> 3;
  int tm = rest % tilesM;
  int tnOuter = rest / tilesM;
  int tn = tnOuter * 8 + tnInner;

  int Kslice = K / splitk;
  int k_begin = blockIdx.y * Kslice;
  int k_end = k_begin + Kslice;

  int tid = threadIdx.x;
  int lane = tid & 63;
  int wave = tid >> 6;
  int wm = wave & 1, wn = wave >> 1;
  int m16 = lane & 15, quad = lane >> 4;

  const unsigned short* Ab = A + (size_t)tm * BM * K;
  const unsigned short* Bb = B + (size_t)tn * BN * K;

  int srow[4], sgcb[4];
#pragma unroll
  for (int it = 0; it < 4; ++it) {
    int blk = it * 256 + tid;
    srow[it] = blk >> 3;
    sgcb[it] = (blk & 7) ^ (srow[it] & 7);
  }
  int ldsbase = (tid & ~63) * 8;

  f32x4 acc[4][4];
#pragma unroll
  for (int i = 0; i < 4; ++i)
#pragma unroll
    for (int j = 0; j < 4; ++j)
#pragma unroll
      for (int t = 0; t < 4; ++t) acc[i][j][t] = 0.0f;

  for (int k0 = k_begin; k0 < k_end; k0 += BK) {
    __syncthreads();
#pragma unroll
    for (int it = 0; it < 4; ++it)
      async_cp16(Ab + (size_t)srow[it] * K + k0 + sgcb[it] * 8,
                 &As[it * 2048 + ldsbase]);
#pragma unroll
    for (int it = 0; it < 4; ++it)
      async_cp16(Bb + (size_t)srow[it] * K + k0 + sgcb[it] * 8,
                 &Bs[it * 2048 + ldsbase]);
    __syncthreads();
#pragma unroll
    for (int kk = 0; kk < 2; ++kk) {
      bf16x8 a[4], b[4];
#pragma unroll
      for (int i = 0; i < 4; ++i) {
        int rr = wm * 64 + i * 16 + m16;
        int cb = (kk << 2) + quad;
        a[i] = *reinterpret_cast<const bf16x8*>(
            &As[rr * BK + ((cb ^ (rr & 7)) << 3)]);
      }
#pragma unroll
      for (int j = 0; j < 4; ++j) {
        int rr = wn * 64 + j * 16 + m16;
        int cb = (kk << 2) + quad;
        b[j] = *reinterpret_cast<const bf16x8*>(
            &Bs[rr * BK + ((cb ^ (rr & 7)) << 3)]);
      }
#pragma unroll
      for (int i = 0; i < 4; ++i)
#pragma unroll
        for (int j = 0; j < 4; ++j)
          acc[i][j] =
              __builtin_amdgcn_mfma_f32_16x16x32_bf16(a[i], b[j], acc[i][j], 0, 0, 0);
    }
  }

  int rowB = tm * BM + wm * 64;
  int colB = tn * BN + wn * 64;
  if constexpr (EPI == 1) {
#pragma unroll
    for (int i = 0; i < 4; ++i)
#pragma unroll
      for (int j = 0; j < 4; ++j) {
        int col = colB + j * 16 + m16;
        int row0 = rowB + i * 16 + quad * 4;
#pragma unroll
        for (int t = 0; t < 4; ++t)
          atomicAdd(&C[(size_t)(row0 + t) * N + col], acc[i][j][t]);
      }
  } else {  // EPI == 4: bias + softplus -> bf16
#pragma unroll
    for (int i = 0; i < 4; ++i)
#pragma unroll
      for (int j = 0; j < 4; ++j) {
        int col = colB + j * 16 + m16;
        float bv = bias[col];
        int row0 = rowB + i * 16 + quad * 4;
#pragma unroll
        for (int t = 0; t < 4; ++t) {
          float x = acc[i][j][t] + bv;
          auxB[(size_t)(row0 + t) * EE + col] = f2bf(softplus_fast(x));
        }
      }
  }
}

// ------------- direct (no-LDS) BT-GEMM for skinny N (x_proj) -------------
__global__ __launch_bounds__(256) void gemm_bt(
    const unsigned short* __restrict__ A,
    const unsigned short* __restrict__ B,
    float* __restrict__ C,
    int M, int N, int K, int tilesN, int splitk) {
  int bid = blockIdx.x;
  int groupSize = 8 * tilesN;
  int g = bid / groupSize, r = bid % groupSize;
  int tm = g * 8 + (r & 7);
  int tn = r >> 3;

  int Kslice = K / splitk;
  int k_begin = blockIdx.y * Kslice;
  int k_end = k_begin + Kslice;

  int tid = threadIdx.x;
  int wave = tid >> 6, lane = tid & 63;
  int wm = wave & 1, wn = wave >> 1;
  int m16 = lane & 15, quad = lane >> 4;
  int rowBase = tm * 64 + wm * 32;
  int colBase = tn * 128 + wn * 64;

  const unsigned short* a0p = A + (size_t)(rowBase + m16) * K + quad * 8;
  const unsigned short* a1p = A + (size_t)(rowBase + 16 + m16) * K + quad * 8;
  const unsigned short* bp[4];
  bool bok[4];
#pragma unroll
  for (int j = 0; j < 4; ++j) {
    int col = colBase + j * 16 + m16;
    bok[j] = (col < N);
    bp[j] = B + (size_t)(bok[j] ? col : 0) * K + quad * 8;
  }

  f32x4 acc[2][4];
#pragma unroll
  for (int i = 0; i < 2; ++i)
#pragma unroll
    for (int j = 0; j < 4; ++j)
#pragma unroll
      for (int t = 0; t < 4; ++t) acc[i][j][t] = 0.0f;

  bf16x8 zero8;
#pragma unroll
  for (int t = 0; t < 8; ++t) zero8[t] = (__bf16)0.0f;

  for (int k = k_begin; k < k_end; k += 32) {
    bf16x8 a0 = *reinterpret_cast<const bf16x8*>(a0p + k);
    bf16x8 a1 = *reinterpret_cast<const bf16x8*>(a1p + k);
    bf16x8 b[4];
#pragma unroll
    for (int j = 0; j < 4; ++j)
      b[j] = bok[j] ? *reinterpret_cast<const bf16x8*>(bp[j] + k) : zero8;
#pragma unroll
    for (int j = 0; j < 4; ++j) {
      acc[0][j] = __builtin_amdgcn_mfma_f32_16x16x32_bf16(a0, b[j], acc[0][j], 0, 0, 0);
      acc[1][j] = __builtin_amdgcn_mfma_f32_16x16x32_bf16(a1, b[j], acc[1][j], 0, 0, 0);
    }
  }

#pragma unroll
  for (int i = 0; i < 2; ++i)
#pragma unroll
    for (int j = 0; j < 4; ++j) {
      int col = colBase + j * 16 + m16;
      if (col >= N) continue;
      int row0 = rowBase + i * 16 + quad * 4;
      if (splitk == 1) {
#pragma unroll
        for (int t = 0; t < 4; ++t)
          C[(size_t)(row0 + t) * N + col] = acc[i][j][t];
      } else {
#pragma unroll
        for (int t = 0; t < 4; ++t)
          atomicAdd(&C[(size_t)(row0 + t) * N + col], acc[i][j][t]);
      }
    }
}

// ------- depthwise causal conv (K=4) + bias + silu, register window -------
__global__ __launch_bounds__(256) void conv_silu_k(
    const float* __restrict__ projh, const float* __restrict__ cw,
    const float* __restrict__ cb, unsigned short* __restrict__ hb) {
  int e = blockIdx.x * 256 + threadIdx.x;
  int l0 = blockIdx.y * 16;
  float w0 = cw[e * 4 + 0], w1 = cw[e * 4 + 1];
  float w2 = cw[e * 4 + 2], w3 = cw[e * 4 + 3];
  float bias = cb[e];
  float xm3 = (l0 >= 3) ? projh[(size_t)(l0 - 3) * EE + e] : 0.0f;
  float xm2 = (l0 >= 2) ? projh[(size_t)(l0 - 2) * EE + e] : 0.0f;
  float xm1 = (l0 >= 1) ? projh[(size_t)(l0 - 1) * EE + e] : 0.0f;
#pragma unroll
  for (int t = 0; t < 16; ++t) {
    int l = l0 + t;
    float x0 = projh[(size_t)l * EE + e];
    float acc = bias + w0 * xm3 + w1 * xm2 + w2 * xm1 + w3 * x0;
    float s = acc / (1.0f + __expf(-acc));
    hb[(size_t)l * EE + e] = f2bf(s);
    xm3 = xm2; xm2 = xm1; xm1 = x0;
  }
}

// ---------------- extract dt rows of ssm -> bf16 [L,128] ----------------
__global__ void dtcast_k(const float* __restrict__ ssm,
                         unsigned short* __restrict__ dtin, int n) {
  int i = blockIdx.x * blockDim.x + threadIdx.x;
  if (i >= n) return;
  int l = i >> 7, r = i & 127;
  dtin[i] = f2bf(ssm[l * 160 + r]);
}

// ================= chunked selective scan (16 states per thread) ===========
__global__ __launch_bounds__(256) void scan_partA(
    const unsigned short* __restrict__ dtb, const unsigned short* __restrict__ hb,
    const float* __restrict__ ssm, const float* __restrict__ A_log,
    float* __restrict__ P, float* __restrict__ S) {
  int e = blockIdx.y * 256 + threadIdx.x;
  int c = blockIdx.x;
  float Aa[16];
#pragma unroll
  for (int q = 0; q < 4; ++q) {
    float4 a = reinterpret_cast<const float4*>(&A_log[(size_t)e * NS])[q];
    Aa[q * 4 + 0] = -__expf(a.x) * 1.44269504f;
    Aa[q * 4 + 1] = -__expf(a.y) * 1.44269504f;
    Aa[q * 4 + 2] = -__expf(a.z) * 1.44269504f;
    Aa[q * 4 + 3] = -__expf(a.w) * 1.44269504f;
  }
  float s[16], p[16];
#pragma unroll
  for (int n = 0; n < 16; ++n) { s[n] = 0.0f; p[n] = 1.0f; }
  int l0 = c * CT;
#pragma unroll 2
  for (int t = 0; t < CT; ++t) {
    int l = l0 + t;
    size_t o = (size_t)l * EE + e;
    float dtv = bf2f(dtb[o]);
    float hv = bf2f(hb[o]);
    float Bv[16];
#pragma unroll
    for (int q = 0; q < 4; ++q)
      *reinterpret_cast<float4*>(&Bv[q * 4]) =
          reinterpret_cast<const float4*>(&ssm[(size_t)l * 160 + 128])[q];
    float z = dtv * hv;
#pragma unroll
    for (int n = 0; n < 16; ++n) {
      float dA = __builtin_amdgcn_exp2f(dtv * Aa[n]);
      s[n] = s[n] * dA + z * Bv[n];
      p[n] *= dA;
    }
  }
  size_t base = ((size_t)c * EE + e) * NS;
#pragma unroll
  for (int q = 0; q < 4; ++q) {
    reinterpret_cast<float4*>(&P[base])[q] = *reinterpret_cast<float4*>(&p[q * 4]);
    reinterpret_cast<float4*>(&S[base])[q] = *reinterpret_cast<float4*>(&s[q * 4]);
  }
}

__global__ __launch_bounds__(256) void scan_chunkB(
    const float* __restrict__ P, float* __restrict__ S) {
  int gidx = blockIdx.x * 256 + threadIdx.x;
  float s = 0.0f;
  float pv = P[gidx], sv = S[gidx];
  for (int c = 0; c < NC; ++c) {
    float pn = 0.0f, sn = 0.0f;
    if (c + 1 < NC) {
      size_t i2 = (size_t)(c + 1) * (EE * NS) + gidx;
      pn = P[i2];
      sn = S[i2];
    }
    float s_next = s * pv + sv;
    S[(size_t)c * (EE * NS) + gidx] = s;
    s = s_next;
    pv = pn; sv = sn;
  }
}

__global__ __launch_bounds__(256) void scan_partC(
    const unsigned short* __restrict__ dtb, const unsigned short* __restrict__ hb,
    const float* __restrict__ ssm, const float* __restrict__ A_log,
    const float* __restrict__ Dp, const unsigned short* __restrict__ sg,
    const float* __restrict__ Sinit, unsigned short* __restrict__ yb) {
  int e = blockIdx.y * 256 + threadIdx.x;
  int c = blockIdx.x;
  float Aa[16];
#pragma unroll
  for (int q = 0; q < 4; ++q) {
    float4 a = reinterpret_cast<const float4*>(&A_log[(size_t)e * NS])[q];
    Aa[q * 4 + 0] = -__expf(a.x) * 1.44269504f;
    Aa[q * 4 + 1] = -__expf(a.y) * 1.44269504f;
    Aa[q * 4 + 2] = -__expf(a.z) * 1.44269504f;
    Aa[q * 4 + 3] = -__expf(a.w) * 1.44269504f;
  }
  float Dv = Dp[e];
  float s[16];
  size_t base = ((size_t)c * EE + e) * NS;
#pragma unroll
  for (int q = 0; q < 4; ++q)
    *reinterpret_cast<float4*>(&s[q * 4]) =
        reinterpret_cast<const float4*>(&Sinit[base])[q];
  int l0 = c * CT;
#pragma unroll 2
  for (int t = 0; t < CT; ++t) {
    int l = l0 + t;
    size_t o = (size_t)l * EE + e;
    float dtv = bf2f(dtb[o]);
    float hv = bf2f(hb[o]);
    float Bv[16], Cv[16];
#pragma unroll
    for (int q = 0; q < 4; ++q) {
      *reinterpret_cast<float4*>(&Bv[q * 4]) =
          reinterpret_cast<const float4*>(&ssm[(size_t)l * 160 + 128])[q];
      *reinterpret_cast<float4*>(&Cv[q * 4]) =
          reinterpret_cast<const float4*>(&ssm[(size_t)l * 160 + 144])[q];
    }
    float z = dtv * hv;
    float y = 0.0f;
#pragma unroll
    for (int n = 0; n < 16; ++n) {
      float dA = __builtin_amdgcn_exp2f(dtv * Aa[n]);
      s[n] = s[n] * dA + z * Bv[n];
      y += s[n] * Cv[n];
    }
    float gv = bf2f(sg[o]);  // pre-activated silu(gate)
    float yv = (y + hv * Dv) * gv;
    yb[o] = f2bf(yv);
  }
}

extern "C" void kernel_launch(void* const* d_in, const int* in_sizes, int n_in,
                              void* d_out, int out_size, void* d_ws, size_t ws_size,
                              hipStream_t stream) {
  const float* hs   = (const float*)d_in[0];
  const float* w1   = (const float*)d_in[1];
  const float* cw   = (const float*)d_in[2];
  const float* cb   = (const float*)d_in[3];
  const float* xw   = (const float*)d_in[4];
  const float* dtw  = (const float*)d_in[5];
  const float* dtb  = (const float*)d_in[6];
  const float* Alog = (const float*)d_in[7];
  const float* Dp   = (const float*)d_in[8];
  const float* ow   = (const float*)d_in[9];
  float* out = (float*)d_out;

  char* ws = (char*)d_ws;
  size_t off = 0;
  auto alloc = [&](size_t b) {
    char* p = ws + off;
    off += (b + 255) & ~(size_t)255;
    return p;
  };
  float* projh = (float*)alloc((size_t)LL * EE * 4);                 // 33.5 MB
  unsigned short* sg  = (unsigned short*)alloc((size_t)LL * EE * 2); // 16.8 MB
  unsigned short* hb  = (unsigned short*)alloc((size_t)LL * EE * 2); // 16.8 MB
  unsigned short* dtb_buf = (unsigned short*)alloc((size_t)LL * EE * 2); // 16.8 MB
  unsigned short* w1b = (unsigned short*)alloc((size_t)2 * EE * HH * 2); // 33.5 MB
  unsigned short* hsb = (unsigned short*)alloc((size_t)LL * HH * 2);
  unsigned short* yb  = (unsigned short*)alloc((size_t)LL * EE * 2);
  unsigned short* owb = (unsigned short*)alloc((size_t)HH * EE * 2);
  unsigned short* xwb = (unsigned short*)alloc((size_t)160 * EE * 2);
  float* ssm = (float*)alloc((size_t)LL * 160 * 4);
  unsigned short* dtin = (unsigned short*)alloc((size_t)LL * RR * 2);
  unsigned short* dtwb = (unsigned short*)alloc((size_t)EE * RR * 2);
  float* Pbuf = (float*)alloc((size_t)NC * EE * NS * 4);             // 16.8 MB
  float* Sbuf = (float*)alloc((size_t)NC * EE * NS * 4);             // 16.8 MB

  // 0) fused prep: all input casts + zero fills in ONE launch
  prep_k<<<P_C6 / 256, 256, 0, stream>>>(hs, hsb, w1, w1b, xw, xwb, dtw, dtwb,
                                         ow, owb, ssm, out);

  // 1) proj = hs @ in_proj_w^T [2048, 8192]; 256^2 8-phase counted-vmcnt.
  //    epilogue: h -> projh f32, gate -> silu -> sg bf16   (77.8us measured)
  {
    int tilesM = LL / 256;          // 8
    int tilesN = (2 * EE) / 256;    // 32  -> 256 blocks, 1/CU
    gemm256<2><<<dim3(tilesM * tilesN, 1), 512, 0, stream>>>(
        hsb, w1b, nullptr, LL, 2 * EE, HH, tilesM, 1, projh, sg);
  }
  // 2) causal depthwise conv + silu -> h (bf16)
  conv_silu_k<<<dim3(EE / 256, LL / 16), 256, 0, stream>>>(projh, cw, cb, hb);
  // 3) ssm = h @ x_proj_w^T [2048, 160] k=4096, split-K=8 (skinny N)
  {
    int tilesN = (160 + 127) / 128, tilesM = LL / 64;
    gemm_bt<<<dim3(tilesM * tilesN, 8), 256, 0, stream>>>(
        hb, xwb, ssm, LL, 160, EE, tilesN, 8);
  }
  // 4) dt input slice -> bf16
  dtcast_k<<<(LL * RR + 255) / 256, 256, 0, stream>>>(ssm, dtin, LL * RR);
  // 5) dt = softplus(dtin @ dt_proj_w^T + dtb) -> bf16   [2048, 4096] k=128
  {
    int tilesN = EE / BN, tilesM = LL / BM;
    gemm_lds_t<4><<<dim3(tilesM * tilesN, 1), 256, 0, stream>>>(
        dtin, dtwb, nullptr, LL, EE, RR, tilesM, 1, dtb, nullptr, dtb_buf);
  }
  // 6) chunked selective scan + gating -> y (bf16)
  scan_partA<<<dim3(NC, EE / 256), 256, 0, stream>>>(dtb_buf, hb, ssm, Alog,
                                                     Pbuf, Sbuf);
  scan_chunkB<<<EE * NS / 256, 256, 0, stream>>>(Pbuf, Sbuf);
  scan_partC<<<dim3(NC, EE / 256), 256, 0, stream>>>(dtb_buf, hb, ssm, Alog, Dp,
                                                     sg, Sbuf, yb);
  // 7) out = y @ out_proj_w^T [2048, 2048] k=4096, split-K=2 — PROVEN 128^2
  //    path (gemm256 split-4 atomic epilogue measured ~95us: cross-XCD atomic
  //    serialization; do not re-switch without fixing the reduction scheme)
  {
    int tilesN = HH / BN, tilesM = LL / BM;
    gemm_lds_t<1><<<dim3(tilesM * tilesN, 2), 256, 0, stream>>>(
        yb, owb, out, LL, HH, EE, tilesM, 2, nullptr, nullptr, nullptr);
  }
}

// Round 6
// 392.975 us; speedup vs baseline: 1.1082x; 1.0590x over previous
//
#include <hip/hip_runtime.h>

#define LL 2048
#define HH 2048
#define EE 4096
#define NS 16
#define RR 128
#define CT 32            // chunk timesteps
#define NC (LL / CT)     // 64 chunks
#define BM 128
#define BN 128
#define BK 64

typedef __bf16 bf16x8 __attribute__((ext_vector_type(8)));
typedef float f32x4 __attribute__((ext_vector_type(4)));

__device__ __forceinline__ unsigned short f2bf(float f) {
  union { float f; unsigned int u; } v; v.f = f;
  unsigned int r = v.u + 0x7fffu + ((v.u >> 16) & 1u);
  return (unsigned short)(r >> 16);
}

__device__ __forceinline__ float bf2f(unsigned short u) {
  union { unsigned int i; float f; } v;
  v.i = ((unsigned int)u) << 16;
  return v.f;
}

// softplus via native transcendentals only (NO libm log1pf — it's a non-inline
// ocml call that forces VGPR save/restore in high-pressure epilogues)
__device__ __forceinline__ float softplus_fast(float x) {
  if (x > 20.0f) return x;
  float e = __builtin_amdgcn_exp2f(1.44269504f * x);
  return 0.69314718f * __builtin_amdgcn_logf(1.0f + e);
}

__device__ __forceinline__ void async_cp16(const unsigned short* g,
                                           unsigned short* l) {
  __builtin_amdgcn_global_load_lds(
      (const __attribute__((address_space(1))) unsigned int*)g,
      (__attribute__((address_space(3))) unsigned int*)l, 16, 0, 0);
}

// ============ fused prep: 5 bf16 casts + 1 zero fill, ONE launch ==========
// (out no longer zeroed: out_proj stores directly, no split-K atomics)
#define P_C0 (LL * HH / 4)               // hs -> hsb
#define P_C1 (P_C0 + 2 * EE * HH / 4)    // w1 -> w1b
#define P_C2 (P_C1 + 160 * EE / 4)       // xw -> xwb
#define P_C3 (P_C2 + EE * RR / 4)        // dtw -> dtwb
#define P_C4 (P_C3 + HH * EE / 4)        // ow -> owb
#define P_C5 (P_C4 + LL * 160 / 4)       // zero ssm

__global__ __launch_bounds__(256) void prep_k(
    const float* __restrict__ hs, unsigned short* __restrict__ hsb,
    const float* __restrict__ w1, unsigned short* __restrict__ w1b,
    const float* __restrict__ xw, unsigned short* __restrict__ xwb,
    const float* __restrict__ dtw, unsigned short* __restrict__ dtwb,
    const float* __restrict__ ow, unsigned short* __restrict__ owb,
    float* __restrict__ ssm) {
  int i = blockIdx.x * 256 + threadIdx.x;
  const float* src = nullptr;
  unsigned short* dst = nullptr;
  int k = 0;
  if (i < P_C0)      { src = hs;  dst = hsb;  k = i; }
  else if (i < P_C1) { src = w1;  dst = w1b;  k = i - P_C0; }
  else if (i < P_C2) { src = xw;  dst = xwb;  k = i - P_C1; }
  else if (i < P_C3) { src = dtw; dst = dtwb; k = i - P_C2; }
  else if (i < P_C4) { src = ow;  dst = owb;  k = i - P_C3; }
  else {
    float4 z; z.x = z.y = z.z = z.w = 0.0f;
    reinterpret_cast<float4*>(ssm)[i - P_C4] = z;
    return;
  }
  float4 v = reinterpret_cast<const float4*>(src)[k];
  ushort4 o;
  o.x = f2bf(v.x); o.y = f2bf(v.y); o.z = f2bf(v.z); o.w = f2bf(v.w);
  reinterpret_cast<ushort4*>(dst)[k] = o;
}

// ============= 256x256 8-phase BT-GEMM (proven: in_proj 76us) ==============
// 512 threads = 8 waves (2Mx4N), per-wave 128x64. BK=64, dbuf LDS 128 KiB.
// 8 phases / 2 K-tiles; counted vmcnt(4)/vmcnt(6); kk-outer MFMA (dep dist 8).
// NOTE: EPI=1 atomic split-K epilogue measured ~95us for out_proj (cross-XCD
// atomic RMW serialization) — do NOT use for split-K.
// EPI: 2 = in_proj (cols<EE -> f32 auxF; cols>=EE -> silu bf16 auxB)
template <int EPI>
__global__ __launch_bounds__(512, 2) void gemm256(
    const unsigned short* __restrict__ A,
    const unsigned short* __restrict__ B,
    float* __restrict__ C,
    int M, int N, int K, int tilesM, int splitk,
    float* __restrict__ auxF, unsigned short* __restrict__ auxB) {
  __shared__ __align__(16) unsigned short As[2][16384];
  __shared__ __align__(16) unsigned short Bs[2][16384];

  int bid = blockIdx.x;
  int tnInner = bid & 7;             // XCD-locality
  int rest = bid >> 3;
  int tm = rest % tilesM;
  int tn = (rest / tilesM) * 8 + tnInner;

  int Kslice = K / splitk;
  int k_begin = blockIdx.y * Kslice;
  int NT = Kslice / 64;              // even, >= 2

  int tid = threadIdx.x;
  int lane = tid & 63;
  int wave = tid >> 6;               // 0..7
  int wm = wave >> 2;                // 0..1
  int wn = wave & 3;                 // 0..3
  int m16 = lane & 15, quad = lane >> 4;

  const unsigned short* Ab = A + (size_t)tm * 256 * K;
  const unsigned short* Bb = B + (size_t)tn * 256 * K;

  int rowS = tid >> 3;
  int gcbS = (tid & 7) ^ (rowS & 7);
  int ldsWB = (tid & ~63) * 8;

  int sw = m16 & 7;
  int coff0 = (quad ^ sw) << 3;
  int coff1 = ((4 + quad) ^ sw) << 3;
  int aoff = (wm * 128 + m16) * 64;
  int boff = (wn * 64 + m16) * 64;

  f32x4 acc[8][4];
#pragma unroll
  for (int i = 0; i < 8; ++i)
#pragma unroll
    for (int j = 0; j < 4; ++j)
#pragma unroll
      for (int t = 0; t < 4; ++t) acc[i][j][t] = 0.0f;

  auto stageA = [&](int bufb, int t, int h) {
    int kt = k_begin + t * 64;
    unsigned short* dst = &As[bufb][0];
#pragma unroll
    for (int c = 2 * h; c < 2 * h + 2; ++c)
      async_cp16(Ab + (size_t)(c * 64 + rowS) * K + kt + gcbS * 8,
                 dst + c * 4096 + ldsWB);
  };
  auto stageB = [&](int bufb, int t, int h) {
    int kt = k_begin + t * 64;
    unsigned short* dst = &Bs[bufb][0];
#pragma unroll
    for (int c = 2 * h; c < 2 * h + 2; ++c)
      async_cp16(Bb + (size_t)(c * 64 + rowS) * K + kt + gcbS * 8,
                 dst + c * 4096 + ldsWB);
  };

  stageA(0, 0, 0); stageA(0, 0, 1);
  stageB(0, 0, 0); stageB(0, 0, 1);
  stageB(1, 1, 0); stageB(1, 1, 1);
  stageA(1, 1, 0);
  asm volatile("s_waitcnt vmcnt(6)" ::: "memory");
  __builtin_amdgcn_s_barrier();

  bf16x8 a[4][2], b0[2][2], b1[2][2];

  for (int t0 = 0; t0 < NT; t0 += 2) {
    int t1 = t0 + 1;
    bool notLast = (t0 + 2 < NT);
    unsigned short* A0 = &As[0][0];
    unsigned short* B0 = &Bs[0][0];
    unsigned short* A1 = &As[1][0];
    unsigned short* B1 = &Bs[1][0];

    // ---- p0 ----
#pragma unroll
    for (int i = 0; i < 4; ++i) {
      a[i][0] = *reinterpret_cast<const bf16x8*>(&A0[aoff + i * 1024 + coff0]);
      a[i][1] = *reinterpret_cast<const bf16x8*>(&A0[aoff + i * 1024 + coff1]);
    }
#pragma unroll
    for (int j = 0; j < 2; ++j) {
      b0[j][0] = *reinterpret_cast<const bf16x8*>(&B0[boff + j * 1024 + coff0]);
      b0[j][1] = *reinterpret_cast<const bf16x8*>(&B0[boff + j * 1024 + coff1]);
    }
    stageA(1, t1, 1);
    __builtin_amdgcn_s_barrier();
    asm volatile("s_waitcnt lgkmcnt(0)" ::: "memory");
    __builtin_amdgcn_sched_barrier(0);
    __builtin_amdgcn_s_setprio(1);
#pragma unroll
    for (int kk = 0; kk < 2; ++kk)
#pragma unroll
      for (int i = 0; i < 4; ++i)
#pragma unroll
        for (int j = 0; j < 2; ++j)
          acc[i][j] = __builtin_amdgcn_mfma_f32_16x16x32_bf16(
              a[i][kk], b0[j][kk], acc[i][j], 0, 0, 0);
    __builtin_amdgcn_s_setprio(0);
    __builtin_amdgcn_s_barrier();

    // ---- p1 ----
#pragma unroll
    for (int j = 0; j < 2; ++j) {
      b1[j][0] = *reinterpret_cast<const bf16x8*>(&B0[boff + (2 + j) * 1024 + coff0]);
      b1[j][1] = *reinterpret_cast<const bf16x8*>(&B0[boff + (2 + j) * 1024 + coff1]);
    }
    __builtin_amdgcn_s_barrier();
    asm volatile("s_waitcnt lgkmcnt(0)" ::: "memory");
    __builtin_amdgcn_sched_barrier(0);
    __builtin_amdgcn_s_setprio(1);
#pragma unroll
    for (int kk = 0; kk < 2; ++kk)
#pragma unroll
      for (int i = 0; i < 4; ++i)
#pragma unroll
        for (int j = 0; j < 2; ++j)
          acc[i][2 + j] = __builtin_amdgcn_mfma_f32_16x16x32_bf16(
              a[i][kk], b1[j][kk], acc[i][2 + j], 0, 0, 0);
    __builtin_amdgcn_s_setprio(0);
    __builtin_amdgcn_s_barrier();

    // ---- p2 ----
#pragma unroll
    for (int i = 0; i < 4; ++i) {
      a[i][0] = *reinterpret_cast<const bf16x8*>(&A0[aoff + (4 + i) * 1024 + coff0]);
      a[i][1] = *reinterpret_cast<const bf16x8*>(&A0[aoff + (4 + i) * 1024 + coff1]);
    }
    if (notLast) stageB(0, t0 + 2, 0);
    __builtin_amdgcn_s_barrier();
    asm volatile("s_waitcnt lgkmcnt(0)" ::: "memory");
    __builtin_amdgcn_sched_barrier(0);
    __builtin_amdgcn_s_setprio(1);
#pragma unroll
    for (int kk = 0; kk < 2; ++kk)
#pragma unroll
      for (int i = 0; i < 4; ++i)
#pragma unroll
        for (int j = 0; j < 2; ++j)
          acc[4 + i][2 + j] = __builtin_amdgcn_mfma_f32_16x16x32_bf16(
              a[i][kk], b1[j][kk], acc[4 + i][2 + j], 0, 0, 0);
    __builtin_amdgcn_s_setprio(0);
    __builtin_amdgcn_s_barrier();

    // ---- p3 ----
    if (notLast) stageB(0, t0 + 2, 1);
    __builtin_amdgcn_s_setprio(1);
#pragma unroll
    for (int kk = 0; kk < 2; ++kk)
#pragma unroll
      for (int i = 0; i < 4; ++i)
#pragma unroll
        for (int j = 0; j < 2; ++j)
          acc[4 + i][j] = __builtin_amdgcn_mfma_f32_16x16x32_bf16(
              a[i][kk], b0[j][kk], acc[4 + i][j], 0, 0, 0);
    __builtin_amdgcn_s_setprio(0);
    if (notLast) {
      asm volatile("s_waitcnt vmcnt(4)" ::: "memory");
    } else {
      asm volatile("s_waitcnt vmcnt(0)" ::: "memory");
    }
    __builtin_amdgcn_s_barrier();

    // ---- p4 ----
#pragma unroll
    for (int i = 0; i < 4; ++i) {
      a[i][0] = *reinterpret_cast<const bf16x8*>(&A1[aoff + i * 1024 + coff0]);
      a[i][1] = *reinterpret_cast<const bf16x8*>(&A1[aoff + i * 1024 + coff1]);
    }
#pragma unroll
    for (int j = 0; j < 2; ++j) {
      b0[j][0] = *reinterpret_cast<const bf16x8*>(&B1[boff + j * 1024 + coff0]);
      b0[j][1] = *reinterpret_cast<const bf16x8*>(&B1[boff + j * 1024 + coff1]);
    }
    if (notLast) stageA(0, t0 + 2, 0);
    __builtin_amdgcn_s_barrier();
    asm volatile("s_waitcnt lgkmcnt(0)" ::: "memory");
    __builtin_amdgcn_sched_barrier(0);
    __builtin_amdgcn_s_setprio(1);
#pragma unroll
    for (int kk = 0; kk < 2; ++kk)
#pragma unroll
      for (int i = 0; i < 4; ++i)
#pragma unroll
        for (int j = 0; j < 2; ++j)
          acc[i][j] = __builtin_amdgcn_mfma_f32_16x16x32_bf16(
              a[i][kk], b0[j][kk], acc[i][j], 0, 0, 0);
    __builtin_amdgcn_s_setprio(0);
    __builtin_amdgcn_s_barrier();

    // ---- p5 ----
#pragma unroll
    for (int j = 0; j < 2; ++j) {
      b1[j][0] = *reinterpret_cast<const bf16x8*>(&B1[boff + (2 + j) * 1024 + coff0]);
      b1[j][1] = *reinterpret_cast<const bf16x8*>(&B1[boff + (2 + j) * 1024 + coff1]);
    }
    if (notLast) stageA(0, t0 + 2, 1);
    __builtin_amdgcn_s_barrier();
    asm volatile("s_waitcnt lgkmcnt(0)" ::: "memory");
    __builtin_amdgcn_sched_barrier(0);
    __builtin_amdgcn_s_setprio(1);
#pragma unroll
    for (int kk = 0; kk < 2; ++kk)
#pragma unroll
      for (int i = 0; i < 4; ++i)
#pragma unroll
        for (int j = 0; j < 2; ++j)
          acc[i][2 + j] = __builtin_amdgcn_mfma_f32_16x16x32_bf16(
              a[i][kk], b1[j][kk], acc[i][2 + j], 0, 0, 0);
    __builtin_amdgcn_s_setprio(0);
    __builtin_amdgcn_s_barrier();

    // ---- p6 ----
#pragma unroll
    for (int i = 0; i < 4; ++i) {
      a[i][0] = *reinterpret_cast<const bf16x8*>(&A1[aoff + (4 + i) * 1024 + coff0]);
      a[i][1] = *reinterpret_cast<const bf16x8*>(&A1[aoff + (4 + i) * 1024 + coff1]);
    }
    if (notLast) stageB(1, t1 + 2, 0);
    __builtin_amdgcn_s_barrier();
    asm volatile("s_waitcnt lgkmcnt(0)" ::: "memory");
    __builtin_amdgcn_sched_barrier(0);
    __builtin_amdgcn_s_setprio(1);
#pragma unroll
    for (int kk = 0; kk < 2; ++kk)
#pragma unroll
      for (int i = 0; i < 4; ++i)
#pragma unroll
        for (int j = 0; j < 2; ++j)
          acc[4 + i][2 + j] = __builtin_amdgcn_mfma_f32_16x16x32_bf16(
              a[i][kk], b1[j][kk], acc[4 + i][2 + j], 0, 0, 0);
    __builtin_amdgcn_s_setprio(0);
    __builtin_amdgcn_s_barrier();

    // ---- p7 ----
    if (notLast) { stageB(1, t1 + 2, 1); stageA(1, t1 + 2, 0); }
    __builtin_amdgcn_s_setprio(1);
#pragma unroll
    for (int kk = 0; kk < 2; ++kk)
#pragma unroll
      for (int i = 0; i < 4; ++i)
#pragma unroll
        for (int j = 0; j < 2; ++j)
          acc[4 + i][j] = __builtin_amdgcn_mfma_f32_16x16x32_bf16(
              a[i][kk], b0[j][kk], acc[4 + i][j], 0, 0, 0);
    __builtin_amdgcn_s_setprio(0);
    if (notLast) {
      asm volatile("s_waitcnt vmcnt(6)" ::: "memory");
    }
    __builtin_amdgcn_s_barrier();
  }

  // ---------------- epilogue ----------------
  int rowB = tm * 256 + wm * 128;
  int colB = tn * 256 + wn * 64;
  if constexpr (EPI == 1) {
#pragma unroll
    for (int mi = 0; mi < 8; ++mi)
#pragma unroll
      for (int nj = 0; nj < 4; ++nj) {
        int col = colB + nj * 16 + m16;
        int row0 = rowB + mi * 16 + quad * 4;
#pragma unroll
        for (int t4 = 0; t4 < 4; ++t4)
          atomicAdd(&C[(size_t)(row0 + t4) * N + col], acc[mi][nj][t4]);
      }
  } else {  // EPI == 2: in_proj epilogue
    if (colB < EE) {
#pragma unroll
      for (int mi = 0; mi < 8; ++mi)
#pragma unroll
        for (int nj = 0; nj < 4; ++nj) {
          int col = colB + nj * 16 + m16;
          int row0 = rowB + mi * 16 + quad * 4;
#pragma unroll
          for (int t4 = 0; t4 < 4; ++t4)
            auxF[(size_t)(row0 + t4) * EE + col] = acc[mi][nj][t4];
        }
    } else {
#pragma unroll
      for (int mi = 0; mi < 8; ++mi)
#pragma unroll
        for (int nj = 0; nj < 4; ++nj) {
          int cg = colB + nj * 16 + m16 - EE;
          int row0 = rowB + mi * 16 + quad * 4;
#pragma unroll
          for (int t4 = 0; t4 < 4; ++t4) {
            float v = acc[mi][nj][t4];
            float s = v / (1.0f + __expf(-v));
            auxB[(size_t)(row0 + t4) * EE + cg] = f2bf(s);
          }
        }
    }
  }
}

// ====== 128x128 8-phase BT-GEMM, NO split-K, direct store (out_proj) =======
// 256 threads = 4 waves (2Mx2N), per-wave 64x64. BK=64, dbuf LDS 64 KiB ->
// 2 blocks/CU (cross-block overlap on top of the pipeline). Same 8-phase
// counted-vmcnt schedule as gemm256; half-tile = 2 staging calls (64 rows).
// Grid must be tilesM*tilesN blocks; K/64 even. C row-major [M][N], coalesced
// direct f32 stores (no atomics, no pre-zero needed).
__global__ __launch_bounds__(256, 2) void gemm128p(
    const unsigned short* __restrict__ A,
    const unsigned short* __restrict__ B,
    float* __restrict__ C,
    int M, int N, int K, int tilesM) {
  __shared__ __align__(16) unsigned short As[2][8192];
  __shared__ __align__(16) unsigned short Bs[2][8192];

  int bid = blockIdx.x;
  int tnInner = bid & 7;             // XCD-locality
  int rest = bid >> 3;
  int tm = rest % tilesM;
  int tn = (rest / tilesM) * 8 + tnInner;

  int NT = K / 64;                   // even (64 here)

  int tid = threadIdx.x;
  int lane = tid & 63;
  int wave = tid >> 6;               // 0..3
  int wm = wave >> 1;                // 0..1
  int wn = wave & 1;                 // 0..1
  int m16 = lane & 15, quad = lane >> 4;

  const unsigned short* Ab = A + (size_t)tm * 128 * K;
  const unsigned short* Bb = B + (size_t)tn * 128 * K;

  // staging: one call = 256 threads x 16B = 32 rows x 64 cols
  int rowS = tid >> 3;                       // 0..31
  int gcbS = (tid & 7) ^ (rowS & 7);
  int ldsWB = (tid & ~63) * 8;               // wave-uniform (8 rows/wave)

  int sw = m16 & 7;
  int coff0 = (quad ^ sw) << 3;
  int coff1 = ((4 + quad) ^ sw) << 3;
  int aoff = (wm * 64 + m16) * 64;
  int boff = (wn * 64 + m16) * 64;

  f32x4 acc[4][4];
#pragma unroll
  for (int i = 0; i < 4; ++i)
#pragma unroll
    for (int j = 0; j < 4; ++j)
#pragma unroll
      for (int t = 0; t < 4; ++t) acc[i][j][t] = 0.0f;

  // half-tile stagers: h in {0,1} -> calls {2h,2h+1} = rows h*64..h*64+63
  auto stageA = [&](int bufb, int t, int h) {
    int kt = t * 64;
    unsigned short* dst = &As[bufb][0];
#pragma unroll
    for (int c = 2 * h; c < 2 * h + 2; ++c)
      async_cp16(Ab + (size_t)(c * 32 + rowS) * K + kt + gcbS * 8,
                 dst + c * 2048 + ldsWB);
  };
  auto stageB = [&](int bufb, int t, int h) {
    int kt = t * 64;
    unsigned short* dst = &Bs[bufb][0];
#pragma unroll
    for (int c = 2 * h; c < 2 * h + 2; ++c)
      async_cp16(Bb + (size_t)(c * 32 + rowS) * K + kt + gcbS * 8,
                 dst + c * 2048 + ldsWB);
  };

  // ---- prologue: tile0 full (8 calls) + B(1)h0,h1 + A(1)h0; vmcnt(6) ----
  stageA(0, 0, 0); stageA(0, 0, 1);
  stageB(0, 0, 0); stageB(0, 0, 1);
  stageB(1, 1, 0); stageB(1, 1, 1);
  stageA(1, 1, 0);
  asm volatile("s_waitcnt vmcnt(6)" ::: "memory");
  __builtin_amdgcn_s_barrier();

  bf16x8 a[2][2], b0[2][2], b1[2][2];

  for (int t0 = 0; t0 < NT; t0 += 2) {
    int t1 = t0 + 1;
    bool notLast = (t0 + 2 < NT);
    unsigned short* A0 = &As[0][0];
    unsigned short* B0 = &Bs[0][0];
    unsigned short* A1 = &As[1][0];
    unsigned short* B1 = &Bs[1][0];

    // ---- p0: reads a[0..1]+b0; stage A(t1)h1; MFMA q00 ----
#pragma unroll
    for (int i = 0; i < 2; ++i) {
      a[i][0] = *reinterpret_cast<const bf16x8*>(&A0[aoff + i * 1024 + coff0]);
      a[i][1] = *reinterpret_cast<const bf16x8*>(&A0[aoff + i * 1024 + coff1]);
    }
#pragma unroll
    for (int j = 0; j < 2; ++j) {
      b0[j][0] = *reinterpret_cast<const bf16x8*>(&B0[boff + j * 1024 + coff0]);
      b0[j][1] = *reinterpret_cast<const bf16x8*>(&B0[boff + j * 1024 + coff1]);
    }
    stageA(1, t1, 1);
    __builtin_amdgcn_s_barrier();
    asm volatile("s_waitcnt lgkmcnt(0)" ::: "memory");
    __builtin_amdgcn_sched_barrier(0);
    __builtin_amdgcn_s_setprio(1);
#pragma unroll
    for (int kk = 0; kk < 2; ++kk)
#pragma unroll
      for (int i = 0; i < 2; ++i)
#pragma unroll
        for (int j = 0; j < 2; ++j)
          acc[i][j] = __builtin_amdgcn_mfma_f32_16x16x32_bf16(
              a[i][kk], b0[j][kk], acc[i][j], 0, 0, 0);
    __builtin_amdgcn_s_setprio(0);
    __builtin_amdgcn_s_barrier();

    // ---- p1: reads b1; MFMA q01 ----
#pragma unroll
    for (int j = 0; j < 2; ++j) {
      b1[j][0] = *reinterpret_cast<const bf16x8*>(&B0[boff + (2 + j) * 1024 + coff0]);
      b1[j][1] = *reinterpret_cast<const bf16x8*>(&B0[boff + (2 + j) * 1024 + coff1]);
    }
    __builtin_amdgcn_s_barrier();
    asm volatile("s_waitcnt lgkmcnt(0)" ::: "memory");
    __builtin_amdgcn_sched_barrier(0);
    __builtin_amdgcn_s_setprio(1);
#pragma unroll
    for (int kk = 0; kk < 2; ++kk)
#pragma unroll
      for (int i = 0; i < 2; ++i)
#pragma unroll
        for (int j = 0; j < 2; ++j)
          acc[i][2 + j] = __builtin_amdgcn_mfma_f32_16x16x32_bf16(
              a[i][kk], b1[j][kk], acc[i][2 + j], 0, 0, 0);
    __builtin_amdgcn_s_setprio(0);
    __builtin_amdgcn_s_barrier();

    // ---- p2: reads a[2..3]; stage B(t0+2)h0; MFMA q11 ----
#pragma unroll
    for (int i = 0; i < 2; ++i) {
      a[i][0] = *reinterpret_cast<const bf16x8*>(&A0[aoff + (2 + i) * 1024 + coff0]);
      a[i][1] = *reinterpret_cast<const bf16x8*>(&A0[aoff + (2 + i) * 1024 + coff1]);
    }
    if (notLast) stageB(0, t0 + 2, 0);
    __builtin_amdgcn_s_barrier();
    asm volatile("s_waitcnt lgkmcnt(0)" ::: "memory");
    __builtin_amdgcn_sched_barrier(0);
    __builtin_amdgcn_s_setprio(1);
#pragma unroll
    for (int kk = 0; kk < 2; ++kk)
#pragma unroll
      for (int i = 0; i < 2; ++i)
#pragma unroll
        for (int j = 0; j < 2; ++j)
          acc[2 + i][2 + j] = __builtin_amdgcn_mfma_f32_16x16x32_bf16(
              a[i][kk], b1[j][kk], acc[2 + i][2 + j], 0, 0, 0);
    __builtin_amdgcn_s_setprio(0);
    __builtin_amdgcn_s_barrier();

    // ---- p3: no reads (b0 in regs); stage B(t0+2)h1; MFMA q10; vmcnt(4) ----
    if (notLast) stageB(0, t0 + 2, 1);
    __builtin_amdgcn_s_setprio(1);
#pragma unroll
    for (int kk = 0; kk < 2; ++kk)
#pragma unroll
      for (int i = 0; i < 2; ++i)
#pragma unroll
        for (int j = 0; j < 2; ++j)
          acc[2 + i][j] = __builtin_amdgcn_mfma_f32_16x16x32_bf16(
              a[i][kk], b0[j][kk], acc[2 + i][j], 0, 0, 0);
    __builtin_amdgcn_s_setprio(0);
    if (notLast) {
      asm volatile("s_waitcnt vmcnt(4)" ::: "memory");
    } else {
      asm volatile("s_waitcnt vmcnt(0)" ::: "memory");
    }
    __builtin_amdgcn_s_barrier();

    // ---- p4: reads a[0..1]+b0 (buf1); stage A(t0+2)h0; MFMA q00 ----
#pragma unroll
    for (int i = 0; i < 2; ++i) {
      a[i][0] = *reinterpret_cast<const bf16x8*>(&A1[aoff + i * 1024 + coff0]);
      a[i][1] = *reinterpret_cast<const bf16x8*>(&A1[aoff + i * 1024 + coff1]);
    }
#pragma unroll
    for (int j = 0; j < 2; ++j) {
      b0[j][0] = *reinterpret_cast<const bf16x8*>(&B1[boff + j * 1024 + coff0]);
      b0[j][1] = *reinterpret_cast<const bf16x8*>(&B1[boff + j * 1024 + coff1]);
    }
    if (notLast) stageA(0, t0 + 2, 0);
    __builtin_amdgcn_s_barrier();
    asm volatile("s_waitcnt lgkmcnt(0)" ::: "memory");
    __builtin_amdgcn_sched_barrier(0);
    __builtin_amdgcn_s_setprio(1);
#pragma unroll
    for (int kk = 0; kk < 2; ++kk)
#pragma unroll
      for (int i = 0; i < 2; ++i)
#pragma unroll
        for (int j = 0; j < 2; ++j)
          acc[i][j] = __builtin_amdgcn_mfma_f32_16x16x32_bf16(
              a[i][kk], b0[j][kk], acc[i][j], 0, 0, 0);
    __builtin_amdgcn_s_setprio(0);
    __builtin_amdgcn_s_barrier();

    // ---- p5: reads b1; stage A(t0+2)h1; MFMA q01 ----
#pragma unroll
    for (int j = 0; j < 2; ++j) {
      b1[j][0] = *reinterpret_cast<const bf16x8*>(&B1[boff + (2 + j) * 1024 + coff0]);
      b1[j][1] = *reinterpret_cast<const bf16x8*>(&B1[boff + (2 + j) * 1024 + coff1]);
    }
    if (notLast) stageA(0, t0 + 2, 1);
    __builtin_amdgcn_s_barrier();
    asm volatile("s_waitcnt lgkmcnt(0)" ::: "memory");
    __builtin_amdgcn_sched_barrier(0);
    __builtin_amdgcn_s_setprio(1);
#pragma unroll
    for (int kk = 0; kk < 2; ++kk)
#pragma unroll
      for (int i = 0; i < 2; ++i)
#pragma unroll
        for (int j = 0; j < 2; ++j)
          acc[i][2 + j] = __builtin_amdgcn_mfma_f32_16x16x32_bf16(
              a[i][kk], b1[j][kk], acc[i][2 + j], 0, 0, 0);
    __builtin_amdgcn_s_setprio(0);
    __builtin_amdgcn_s_barrier();

    // ---- p6: reads a[2..3]; stage B(t1+2)h0; MFMA q11 ----
#pragma unroll
    for (int i = 0; i < 2; ++i) {
      a[i][0] = *reinterpret_cast<const bf16x8*>(&A1[aoff + (2 + i) * 1024 + coff0]);
      a[i][1] = *reinterpret_cast<const bf16x8*>(&A1[aoff + (2 + i) * 1024 + coff1]);
    }
    if (notLast) stageB(1, t1 + 2, 0);
    __builtin_amdgcn_s_barrier();
    asm volatile("s_waitcnt lgkmcnt(0)" ::: "memory");
    __builtin_amdgcn_sched_barrier(0);
    __builtin_amdgcn_s_setprio(1);
#pragma unroll
    for (int kk = 0; kk < 2; ++kk)
#pragma unroll
      for (int i = 0; i < 2; ++i)
#pragma unroll
        for (int j = 0; j < 2; ++j)
          acc[2 + i][2 + j] = __builtin_amdgcn_mfma_f32_16x16x32_bf16(
              a[i][kk], b1[j][kk], acc[2 + i][2 + j], 0, 0, 0);
    __builtin_amdgcn_s_setprio(0);
    __builtin_amdgcn_s_barrier();

    // ---- p7: no reads; stage B(t1+2)h1 + A(t1+2)h0; MFMA q10; vmcnt(6) ----
    if (notLast) { stageB(1, t1 + 2, 1); stageA(1, t1 + 2, 0); }
    __builtin_amdgcn_s_setprio(1);
#pragma unroll
    for (int kk = 0; kk < 2; ++kk)
#pragma unroll
      for (int i = 0; i < 2; ++i)
#pragma unroll
        for (int j = 0; j < 2; ++j)
          acc[2 + i][j] = __builtin_amdgcn_mfma_f32_16x16x32_bf16(
              a[i][kk], b0[j][kk], acc[2 + i][j], 0, 0, 0);
    __builtin_amdgcn_s_setprio(0);
    if (notLast) {
      asm volatile("s_waitcnt vmcnt(6)" ::: "memory");
    }
    __builtin_amdgcn_s_barrier();
  }

  // ---- epilogue: direct coalesced store ----
  int rowB = tm * 128 + wm * 64;
  int colB = tn * 128 + wn * 64;
#pragma unroll
  for (int mi = 0; mi < 4; ++mi)
#pragma unroll
    for (int nj = 0; nj < 4; ++nj) {
      int col = colB + nj * 16 + m16;
      int row0 = rowB + mi * 16 + quad * 4;
#pragma unroll
      for (int t4 = 0; t4 < 4; ++t4)
        C[(size_t)(row0 + t4) * N + col] = acc[mi][nj][t4];
    }
}

// ============ LDS-staged bf16 BT-GEMM (128x128) — dt_proj ==================
// EPI: 1 = f32 atomicAdd (split-K)   4 = +bias[col], softplus, bf16 to auxB
template <int EPI>
__global__ __launch_bounds__(256) void gemm_lds_t(
    const unsigned short* __restrict__ A,
    const unsigned short* __restrict__ B,
    float* __restrict__ C,
    int M, int N, int K, int tilesM, int splitk,
    const float* __restrict__ bias, float* __restrict__ auxF,
    unsigned short* __restrict__ auxB) {
  __shared__ __align__(16) unsigned short As[BM * BK];
  __shared__ __align__(16) unsigned short Bs[BN * BK];

  int bid = blockIdx.x;
  int tnInner = bid & 7;
  int rest = bid >> 3;
  int tm = rest % tilesM;
  int tnOuter = rest / tilesM;
  int tn = tnOuter * 8 + tnInner;

  int Kslice = K / splitk;
  int k_begin = blockIdx.y * Kslice;
  int k_end = k_begin + Kslice;

  int tid = threadIdx.x;
  int lane = tid & 63;
  int wave = tid >> 6;
  int wm = wave & 1, wn = wave >> 1;
  int m16 = lane & 15, quad = lane >> 4;

  const unsigned short* Ab = A + (size_t)tm * BM * K;
  const unsigned short* Bb = B + (size_t)tn * BN * K;

  int srow[4], sgcb[4];
#pragma unroll
  for (int it = 0; it < 4; ++it) {
    int blk = it * 256 + tid;
    srow[it] = blk >> 3;
    sgcb[it] = (blk & 7) ^ (srow[it] & 7);
  }
  int ldsbase = (tid & ~63) * 8;

  f32x4 acc[4][4];
#pragma unroll
  for (int i = 0; i < 4; ++i)
#pragma unroll
    for (int j = 0; j < 4; ++j)
#pragma unroll
      for (int t = 0; t < 4; ++t) acc[i][j][t] = 0.0f;

  for (int k0 = k_begin; k0 < k_end; k0 += BK) {
    __syncthreads();
#pragma unroll
    for (int it = 0; it < 4; ++it)
      async_cp16(Ab + (size_t)srow[it] * K + k0 + sgcb[it] * 8,
                 &As[it * 2048 + ldsbase]);
#pragma unroll
    for (int it = 0; it < 4; ++it)
      async_cp16(Bb + (size_t)srow[it] * K + k0 + sgcb[it] * 8,
                 &Bs[it * 2048 + ldsbase]);
    __syncthreads();
#pragma unroll
    for (int kk = 0; kk < 2; ++kk) {
      bf16x8 a[4], b[4];
#pragma unroll
      for (int i = 0; i < 4; ++i) {
        int rr = wm * 64 + i * 16 + m16;
        int cb = (kk << 2) + quad;
        a[i] = *reinterpret_cast<const bf16x8*>(
            &As[rr * BK + ((cb ^ (rr & 7)) << 3)]);
      }
#pragma unroll
      for (int j = 0; j < 4; ++j) {
        int rr = wn * 64 + j * 16 + m16;
        int cb = (kk << 2) + quad;
        b[j] = *reinterpret_cast<const bf16x8*>(
            &Bs[rr * BK + ((cb ^ (rr & 7)) << 3)]);
      }
#pragma unroll
      for (int i = 0; i < 4; ++i)
#pragma unroll
        for (int j = 0; j < 4; ++j)
          acc[i][j] =
              __builtin_amdgcn_mfma_f32_16x16x32_bf16(a[i], b[j], acc[i][j], 0, 0, 0);
    }
  }

  int rowB = tm * BM + wm * 64;
  int colB = tn * BN + wn * 64;
  if constexpr (EPI == 1) {
#pragma unroll
    for (int i = 0; i < 4; ++i)
#pragma unroll
      for (int j = 0; j < 4; ++j) {
        int col = colB + j * 16 + m16;
        int row0 = rowB + i * 16 + quad * 4;
#pragma unroll
        for (int t = 0; t < 4; ++t)
          atomicAdd(&C[(size_t)(row0 + t) * N + col], acc[i][j][t]);
      }
  } else {  // EPI == 4: bias + softplus -> bf16
#pragma unroll
    for (int i = 0; i < 4; ++i)
#pragma unroll
      for (int j = 0; j < 4; ++j) {
        int col = colB + j * 16 + m16;
        float bv = bias[col];
        int row0 = rowB + i * 16 + quad * 4;
#pragma unroll
        for (int t = 0; t < 4; ++t) {
          float x = acc[i][j][t] + bv;
          auxB[(size_t)(row0 + t) * EE + col] = f2bf(softplus_fast(x));
        }
      }
  }
}

// ------------- direct (no-LDS) BT-GEMM for skinny N (x_proj) -------------
__global__ __launch_bounds__(256) void gemm_bt(
    const unsigned short* __restrict__ A,
    const unsigned short* __restrict__ B,
    float* __restrict__ C,
    int M, int N, int K, int tilesN, int splitk) {
  int bid = blockIdx.x;
  int groupSize = 8 * tilesN;
  int g = bid / groupSize, r = bid % groupSize;
  int tm = g * 8 + (r & 7);
  int tn = r >> 3;

  int Kslice = K / splitk;
  int k_begin = blockIdx.y * Kslice;
  int k_end = k_begin + Kslice;

  int tid = threadIdx.x;
  int wave = tid >> 6, lane = tid & 63;
  int wm = wave & 1, wn = wave >> 1;
  int m16 = lane & 15, quad = lane >> 4;
  int rowBase = tm * 64 + wm * 32;
  int colBase = tn * 128 + wn * 64;

  const unsigned short* a0p = A + (size_t)(rowBase + m16) * K + quad * 8;
  const unsigned short* a1p = A + (size_t)(rowBase + 16 + m16) * K + quad * 8;
  const unsigned short* bp[4];
  bool bok[4];
#pragma unroll
  for (int j = 0; j < 4; ++j) {
    int col = colBase + j * 16 + m16;
    bok[j] = (col < N);
    bp[j] = B + (size_t)(bok[j] ? col : 0) * K + quad * 8;
  }

  f32x4 acc[2][4];
#pragma unroll
  for (int i = 0; i < 2; ++i)
#pragma unroll
    for (int j = 0; j < 4; ++j)
#pragma unroll
      for (int t = 0; t < 4; ++t) acc[i][j][t] = 0.0f;

  bf16x8 zero8;
#pragma unroll
  for (int t = 0; t < 8; ++t) zero8[t] = (__bf16)0.0f;

  for (int k = k_begin; k < k_end; k += 32) {
    bf16x8 a0 = *reinterpret_cast<const bf16x8*>(a0p + k);
    bf16x8 a1 = *reinterpret_cast<const bf16x8*>(a1p + k);
    bf16x8 b[4];
#pragma unroll
    for (int j = 0; j < 4; ++j)
      b[j] = bok[j] ? *reinterpret_cast<const bf16x8*>(bp[j] + k) : zero8;
#pragma unroll
    for (int j = 0; j < 4; ++j) {
      acc[0][j] = __builtin_amdgcn_mfma_f32_16x16x32_bf16(a0, b[j], acc[0][j], 0, 0, 0);
      acc[1][j] = __builtin_amdgcn_mfma_f32_16x16x32_bf16(a1, b[j], acc[1][j], 0, 0, 0);
    }
  }

#pragma unroll
  for (int i = 0; i < 2; ++i)
#pragma unroll
    for (int j = 0; j < 4; ++j) {
      int col = colBase + j * 16 + m16;
      if (col >= N) continue;
      int row0 = rowBase + i * 16 + quad * 4;
      if (splitk == 1) {
#pragma unroll
        for (int t = 0; t < 4; ++t)
          C[(size_t)(row0 + t) * N + col] = acc[i][j][t];
      } else {
#pragma unroll
        for (int t = 0; t < 4; ++t)
          atomicAdd(&C[(size_t)(row0 + t) * N + col], acc[i][j][t]);
      }
    }
}

// ------- depthwise causal conv (K=4) + bias + silu, register window -------
__global__ __launch_bounds__(256) void conv_silu_k(
    const float* __restrict__ projh, const float* __restrict__ cw,
    const float* __restrict__ cb, unsigned short* __restrict__ hb) {
  int e = blockIdx.x * 256 + threadIdx.x;
  int l0 = blockIdx.y * 16;
  float w0 = cw[e * 4 + 0], w1 = cw[e * 4 + 1];
  float w2 = cw[e * 4 + 2], w3 = cw[e * 4 + 3];
  float bias = cb[e];
  float xm3 = (l0 >= 3) ? projh[(size_t)(l0 - 3) * EE + e] : 0.0f;
  float xm2 = (l0 >= 2) ? projh[(size_t)(l0 - 2) * EE + e] : 0.0f;
  float xm1 = (l0 >= 1) ? projh[(size_t)(l0 - 1) * EE + e] : 0.0f;
#pragma unroll
  for (int t = 0; t < 16; ++t) {
    int l = l0 + t;
    float x0 = projh[(size_t)l * EE + e];
    float acc = bias + w0 * xm3 + w1 * xm2 + w2 * xm1 + w3 * x0;
    float s = acc / (1.0f + __expf(-acc));
    hb[(size_t)l * EE + e] = f2bf(s);
    xm3 = xm2; xm2 = xm1; xm1 = x0;
  }
}

// ---------------- extract dt rows of ssm -> bf16 [L,128] ----------------
__global__ void dtcast_k(const float* __restrict__ ssm,
                         unsigned short* __restrict__ dtin, int n) {
  int i = blockIdx.x * blockDim.x + threadIdx.x;
  if (i >= n) return;
  int l = i >> 7, r = i & 127;
  dtin[i] = f2bf(ssm[l * 160 + r]);
}

// ================= chunked selective scan (16 states per thread) ===========
__global__ __launch_bounds__(256) void scan_partA(
    const unsigned short* __restrict__ dtb, const unsigned short* __restrict__ hb,
    const float* __restrict__ ssm, const float* __restrict__ A_log,
    float* __restrict__ P, float* __restrict__ S) {
  int e = blockIdx.y * 256 + threadIdx.x;
  int c = blockIdx.x;
  float Aa[16];
#pragma unroll
  for (int q = 0; q < 4; ++q) {
    float4 a = reinterpret_cast<const float4*>(&A_log[(size_t)e * NS])[q];
    Aa[q * 4 + 0] = -__expf(a.x) * 1.44269504f;
    Aa[q * 4 + 1] = -__expf(a.y) * 1.44269504f;
    Aa[q * 4 + 2] = -__expf(a.z) * 1.44269504f;
    Aa[q * 4 + 3] = -__expf(a.w) * 1.44269504f;
  }
  float s[16], p[16];
#pragma unroll
  for (int n = 0; n < 16; ++n) { s[n] = 0.0f; p[n] = 1.0f; }
  int l0 = c * CT;
#pragma unroll 2
  for (int t = 0; t < CT; ++t) {
    int l = l0 + t;
    size_t o = (size_t)l * EE + e;
    float dtv = bf2f(dtb[o]);
    float hv = bf2f(hb[o]);
    float Bv[16];
#pragma unroll
    for (int q = 0; q < 4; ++q)
      *reinterpret_cast<float4*>(&Bv[q * 4]) =
          reinterpret_cast<const float4*>(&ssm[(size_t)l * 160 + 128])[q];
    float z = dtv * hv;
#pragma unroll
    for (int n = 0; n < 16; ++n) {
      float dA = __builtin_amdgcn_exp2f(dtv * Aa[n]);
      s[n] = s[n] * dA + z * Bv[n];
      p[n] *= dA;
    }
  }
  size_t base = ((size_t)c * EE + e) * NS;
#pragma unroll
  for (int q = 0; q < 4; ++q) {
    reinterpret_cast<float4*>(&P[base])[q] = *reinterpret_cast<float4*>(&p[q * 4]);
    reinterpret_cast<float4*>(&S[base])[q] = *reinterpret_cast<float4*>(&s[q * 4]);
  }
}

__global__ __launch_bounds__(256) void scan_chunkB(
    const float* __restrict__ P, float* __restrict__ S) {
  int gidx = blockIdx.x * 256 + threadIdx.x;
  float s = 0.0f;
  float pv = P[gidx], sv = S[gidx];
  for (int c = 0; c < NC; ++c) {
    float pn = 0.0f, sn = 0.0f;
    if (c + 1 < NC) {
      size_t i2 = (size_t)(c + 1) * (EE * NS) + gidx;
      pn = P[i2];
      sn = S[i2];
    }
    float s_next = s * pv + sv;
    S[(size_t)c * (EE * NS) + gidx] = s;
    s = s_next;
    pv = pn; sv = sn;
  }
}

__global__ __launch_bounds__(256) void scan_partC(
    const unsigned short* __restrict__ dtb, const unsigned short* __restrict__ hb,
    const float* __restrict__ ssm, const float* __restrict__ A_log,
    const float* __restrict__ Dp, const unsigned short* __restrict__ sg,
    const float* __restrict__ Sinit, unsigned short* __restrict__ yb) {
  int e = blockIdx.y * 256 + threadIdx.x;
  int c = blockIdx.x;
  float Aa[16];
#pragma unroll
  for (int q = 0; q < 4; ++q) {
    float4 a = reinterpret_cast<const float4*>(&A_log[(size_t)e * NS])[q];
    Aa[q * 4 + 0] = -__expf(a.x) * 1.44269504f;
    Aa[q * 4 + 1] = -__expf(a.y) * 1.44269504f;
    Aa[q * 4 + 2] = -__expf(a.z) * 1.44269504f;
    Aa[q * 4 + 3] = -__expf(a.w) * 1.44269504f;
  }
  float Dv = Dp[e];
  float s[16];
  size_t base = ((size_t)c * EE + e) * NS;
#pragma unroll
  for (int q = 0; q < 4; ++q)
    *reinterpret_cast<float4*>(&s[q * 4]) =
        reinterpret_cast<const float4*>(&Sinit[base])[q];
  int l0 = c * CT;
#pragma unroll 2
  for (int t = 0; t < CT; ++t) {
    int l = l0 + t;
    size_t o = (size_t)l * EE + e;
    float dtv = bf2f(dtb[o]);
    float hv = bf2f(hb[o]);
    float Bv[16], Cv[16];
#pragma unroll
    for (int q = 0; q < 4; ++q) {
      *reinterpret_cast<float4*>(&Bv[q * 4]) =
          reinterpret_cast<const float4*>(&ssm[(size_t)l * 160 + 128])[q];
      *reinterpret_cast<float4*>(&Cv[q * 4]) =
          reinterpret_cast<const float4*>(&ssm[(size_t)l * 160 + 144])[q];
    }
    float z = dtv * hv;
    float y = 0.0f;
#pragma unroll
    for (int n = 0; n < 16; ++n) {
      float dA = __builtin_amdgcn_exp2f(dtv * Aa[n]);
      s[n] = s[n] * dA + z * Bv[n];
      y += s[n] * Cv[n];
    }
    float gv = bf2f(sg[o]);  // pre-activated silu(gate)
    float yv = (y + hv * Dv) * gv;
    yb[o] = f2bf(yv);
  }
}

extern "C" void kernel_launch(void* const* d_in, const int* in_sizes, int n_in,
                              void* d_out, int out_size, void* d_ws, size_t ws_size,
                              hipStream_t stream) {
  const float* hs   = (const float*)d_in[0];
  const float* w1   = (const float*)d_in[1];
  const float* cw   = (const float*)d_in[2];
  const float* cb   = (const float*)d_in[3];
  const float* xw   = (const float*)d_in[4];
  const float* dtw  = (const float*)d_in[5];
  const float* dtb  = (const float*)d_in[6];
  const float* Alog = (const float*)d_in[7];
  const float* Dp   = (const float*)d_in[8];
  const float* ow   = (const float*)d_in[9];
  float* out = (float*)d_out;

  char* ws = (char*)d_ws;
  size_t off = 0;
  auto alloc = [&](size_t b) {
    char* p = ws + off;
    off += (b + 255) & ~(size_t)255;
    return p;
  };
  float* projh = (float*)alloc((size_t)LL * EE * 4);                 // 33.5 MB
  unsigned short* sg  = (unsigned short*)alloc((size_t)LL * EE * 2); // 16.8 MB
  unsigned short* hb  = (unsigned short*)alloc((size_t)LL * EE * 2); // 16.8 MB
  unsigned short* dtb_buf = (unsigned short*)alloc((size_t)LL * EE * 2); // 16.8 MB
  unsigned short* w1b = (unsigned short*)alloc((size_t)2 * EE * HH * 2); // 33.5 MB
  unsigned short* hsb = (unsigned short*)alloc((size_t)LL * HH * 2);
  unsigned short* yb  = (unsigned short*)alloc((size_t)LL * EE * 2);
  unsigned short* owb = (unsigned short*)alloc((size_t)HH * EE * 2);
  unsigned short* xwb = (unsigned short*)alloc((size_t)160 * EE * 2);
  float* ssm = (float*)alloc((size_t)LL * 160 * 4);
  unsigned short* dtin = (unsigned short*)alloc((size_t)LL * RR * 2);
  unsigned short* dtwb = (unsigned short*)alloc((size_t)EE * RR * 2);
  float* Pbuf = (float*)alloc((size_t)NC * EE * NS * 4);             // 16.8 MB
  float* Sbuf = (float*)alloc((size_t)NC * EE * NS * 4);             // 16.8 MB

  // 0) fused prep: all input casts + ssm zero in ONE launch (out not zeroed:
  //    out_proj stores directly now)
  prep_k<<<P_C5 / 256, 256, 0, stream>>>(hs, hsb, w1, w1b, xw, xwb, dtw, dtwb,
                                         ow, owb, ssm);

  // 1) proj = hs @ in_proj_w^T [2048, 8192]; 256^2 8-phase counted-vmcnt.
  //    epilogue: h -> projh f32, gate -> silu -> sg bf16   (76us measured)
  {
    int tilesM = LL / 256;          // 8
    int tilesN = (2 * EE) / 256;    // 32  -> 256 blocks, 1/CU
    gemm256<2><<<dim3(tilesM * tilesN, 1), 512, 0, stream>>>(
        hsb, w1b, nullptr, LL, 2 * EE, HH, tilesM, 1, projh, sg);
  }
  // 2) causal depthwise conv + silu -> h (bf16)
  conv_silu_k<<<dim3(EE / 256, LL / 16), 256, 0, stream>>>(projh, cw, cb, hb);
  // 3) ssm = h @ x_proj_w^T [2048, 160] k=4096, split-K=8 (skinny N)
  {
    int tilesN = (160 + 127) / 128, tilesM = LL / 64;
    gemm_bt<<<dim3(tilesM * tilesN, 8), 256, 0, stream>>>(
        hb, xwb, ssm, LL, 160, EE, tilesN, 8);
  }
  // 4) dt input slice -> bf16
  dtcast_k<<<(LL * RR + 255) / 256, 256, 0, stream>>>(ssm, dtin, LL * RR);
  // 5) dt = softplus(dtin @ dt_proj_w^T + dtb) -> bf16   [2048, 4096] k=128
  {
    int tilesN = EE / BN, tilesM = LL / BM;
    gemm_lds_t<4><<<dim3(tilesM * tilesN, 1), 256, 0, stream>>>(
        dtin, dtwb, nullptr, LL, EE, RR, tilesM, 1, dtb, nullptr, dtb_buf);
  }
  // 6) chunked selective scan + gating -> y (bf16)
  scan_partA<<<dim3(NC, EE / 256), 256, 0, stream>>>(dtb_buf, hb, ssm, Alog,
                                                     Pbuf, Sbuf);
  scan_chunkB<<<EE * NS / 256, 256, 0, stream>>>(Pbuf, Sbuf);
  scan_partC<<<dim3(NC, EE / 256), 256, 0, stream>>>(dtb_buf, hb, ssm, Alog, Dp,
                                                     sg, Sbuf, yb);
  // 7) out = y @ out_proj_w^T [2048, 2048] k=4096; 128^2 8-phase pipeline,
  //    NO split-K: 16x16 = 256 tiles = 1 block/CU, NT=64, 2 blocks/CU
  //    residency (64KB LDS), direct f32 stores (no atomics, no pre-zero)
  {
    int tilesM = LL / 128, tilesN = HH / 128;  // 16 x 16 = 256
    gemm128p<<<dim3(tilesM * tilesN, 1), 256, 0, stream>>>(
        yb, owb, out, LL, HH, EE, tilesM);
  }
}